// Round 7
// baseline (194.927 us; speedup 1.0000x reference)
//
#include <hip/hip_runtime.h>
#include <math.h>

// Problem dims (fixed by the reference)
#define B_ 8
#define L_ 8192
#define H_ 128
#define N_ 32
#define C_ 128   // chunks along L (= threads per k_s4d block)
#define T_ 64    // chunk length (C_*T_ == L_)

// ws layout:
//   Whi ushort[256*128] @ 0        (64 KB)  bf16 hi part of out_w, [g][h]
//   Wlo ushort[256*128] @ 65536    (64 KB)  bf16 lo part (w - hi)
//   gyb ushort[B_*H_*L_] @ 131072  (16 MB)  bf16 gy, [b][T'(128)][h(128)][v(64)]
//   part float[1024]    @ 16908288 (4 KB)   per-block k_mix partials
// l' = T'*64+v = t*128+c (fixed permutation of l; mix+pool is order-invariant)

typedef __attribute__((ext_vector_type(8))) short short8;
typedef __attribute__((ext_vector_type(4))) float f32x4;

__device__ __forceinline__ unsigned short f2bf(float f) {
    unsigned int u = __float_as_uint(f);
    return (unsigned short)((u + 0x7FFFu + ((u >> 16) & 1u)) >> 16);
}
__device__ __forceinline__ float bf2f(unsigned short h) {
    return __uint_as_float(((unsigned int)h) << 16);
}

__device__ __forceinline__ float gelu_tanh(float y) {
    float t = 0.7978845608028654f * fmaf(0.044715f, y * y * y, y);
    float e = __expf(2.f * t);
    float th = 1.f - __fdividef(2.f, e + 1.f);
    return 0.5f * y * (1.f + th);
}

// ---------------------------------------------------------------------------
// k_setup: split out_w into bf16 hi/lo ([g][h] = MFMA A layout)
// ---------------------------------------------------------------------------
__global__ __launch_bounds__(256) void k_setup(
    const float* __restrict__ out_w, unsigned short* __restrict__ Whi,
    unsigned short* __restrict__ Wlo)
{
    int idx = blockIdx.x * 256 + threadIdx.x;  // 0..32767 = g*128+h
    float w = out_w[idx];
    unsigned short hi = f2bf(w);
    Whi[idx] = hi;
    Wlo[idx] = f2bf(w - bf2f(hi));
}

// ---------------------------------------------------------------------------
// k_s4d: fused encoder + chunked S4D scan + skip + GELU -> bf16 gy.
// Block=(b,h), 128 threads (2 waves), thread = chunk c.
// PLAIN __launch_bounds__(128): min-wave bounds spill (R3: 7x, R5: 1.5x).
// Phase-1 u-tile = 16 (R6's tile=8 kept VALU work equal but lost ILP: 98->128us).
// ---------------------------------------------------------------------------
__global__ __launch_bounds__(128) void k_s4d(
    const float* __restrict__ x, const float* __restrict__ enc_w,
    const float* __restrict__ enc_b, const float* __restrict__ log_dt,
    const float* __restrict__ log_A_real, const float* __restrict__ A_imag,
    const float* __restrict__ C_re, const float* __restrict__ C_im,
    const float* __restrict__ Dp, unsigned short* __restrict__ gyb)
{
    const int bh = blockIdx.x;
    const int b = bh >> 7, h = bh & (H_ - 1);
    const int c = threadIdx.x;
    const int lane = c & 63, wv = c >> 6;

    __shared__ float4 cw4[N_];        // (wr, wi, coef_r, coef_i)
    __shared__ float4 pw[N_];         // (w2r, w2i, wr, wi)
    __shared__ float2 wTpow[7][N_];   // wT^(2^k)
    __shared__ float2 Sx[N_][64];     // wave-0 inclusive scans (16 KB)

    if (c < N_) {
        int idx = h * N_ + c;
        float dt = expf(log_dt[h]);
        float Ar = -expf(log_A_real[idx]);
        float Ai = A_imag[idx];
        float ar = dt * Ar, ai = dt * Ai;
        float er = expf(ar);
        float wr = er * cosf(ai), wi = er * sinf(ai);
        float numr = wr - 1.f, numi = wi;
        float inv = 1.f / (Ar * Ar + Ai * Ai);
        float qr = (numr * Ar + numi * Ai) * inv;
        float qi = (numi * Ar - numr * Ai) * inv;
        cw4[c] = make_float4(wr, wi, C_re[idx] * qr - C_im[idx] * qi,
                                     C_re[idx] * qi + C_im[idx] * qr);
        pw[c] = make_float4(wr * wr - wi * wi, 2.f * wr * wi, wr, wi);
        float erT = expf(ar * (float)T_);
        float pr = erT * cosf(ai * (float)T_), pi = erT * sinf(ai * (float)T_);
#pragma unroll
        for (int k = 0; k < 7; ++k) {
            wTpow[k][c] = make_float2(pr, pi);
            float nr = pr * pr - pi * pi;
            pi = 2.f * pr * pi; pr = nr;
        }
    }
    __syncthreads();

    const float2* xb = (const float2*)x + (size_t)b * L_ + c * T_;
    const float ew0 = enc_w[h], ew1 = enc_w[H_ + h], eb = enc_b[h];

    // ---- Phase 1: E[c] via w^2 double-steps; 16-timestep u tile, n by 4 ----
    float zr[N_], zi[N_];
#pragma unroll
    for (int n = 0; n < N_; ++n) { zr[n] = 0.f; zi[n] = 0.f; }

#pragma unroll 1
    for (int tt = 0; tt < T_ / 16; ++tt) {      // 4 tiles of 16 timesteps
        float u[16];
        const float4* xq = (const float4*)xb + tt * 8;
#pragma unroll
        for (int j = 0; j < 8; ++j) {
            float4 xv = xq[j];
            u[2 * j]     = fmaf(xv.x, ew0, fmaf(xv.y, ew1, eb));
            u[2 * j + 1] = fmaf(xv.z, ew0, fmaf(xv.w, ew1, eb));
        }
#pragma unroll
        for (int ng = 0; ng < 8; ++ng) {
            float4 q[4];
#pragma unroll
            for (int m = 0; m < 4; ++m) q[m] = pw[ng * 4 + m];
#pragma unroll
            for (int m = 0; m < 4; ++m) {
                int n = ng * 4 + m;
                float ar_ = zr[n], ai_ = zi[n];
#pragma unroll
                for (int t2 = 0; t2 < 8; ++t2) {
                    float ua = u[2 * t2], ub = u[2 * t2 + 1];
                    float mr = fmaf(q[m].z, ua, ub);
                    float mi = q[m].w * ua;
                    float nr = fmaf(q[m].x, ar_, fmaf(-q[m].y, ai_, mr));
                    ai_ = fmaf(q[m].x, ai_, fmaf(q[m].y, ar_, mi));
                    ar_ = nr;
                }
                zr[n] = ar_; zi[n] = ai_;
            }
        }
    }

    // ---- Phase 2: scan over chunks ----
#pragma unroll
    for (int k = 0; k < 6; ++k) {
        int s = 1 << k;
        float mask = (lane >= s) ? 1.f : 0.f;
#pragma unroll
        for (int n = 0; n < N_; ++n) {
            float2 q = wTpow[k][n];
            float vr = __shfl_up(zr[n], s, 64);
            float vi = __shfl_up(zi[n], s, 64);
            float adr = fmaf(q.x, vr, -(q.y * vi));
            float adi = fmaf(q.x, vi, q.y * vr);
            zr[n] = fmaf(mask, adr, zr[n]);
            zi[n] = fmaf(mask, adi, zi[n]);
        }
    }
    if (wv == 0) {
#pragma unroll
        for (int n = 0; n < N_; ++n) Sx[n][lane] = make_float2(zr[n], zi[n]);
    }
    __syncthreads();
    if (wv == 1) {
#pragma unroll
        for (int n = 0; n < N_; ++n) {
            float2 q = wTpow[6][n];
            float2 v = Sx[n][lane];
            zr[n] = fmaf(q.x, v.x, fmaf(-q.y, v.y, zr[n]));
            zi[n] = fmaf(q.x, v.y, fmaf(q.y, v.x, zi[n]));
        }
    }
    {
        bool l0 = (lane == 0);
#pragma unroll
        for (int n = 0; n < N_; ++n) {
            float2 bv = Sx[n][63];
            float br = (wv == 1) ? bv.x : 0.f;
            float bi = (wv == 1) ? bv.y : 0.f;
            float tr = __shfl_up(zr[n], 1, 64);
            float ti = __shfl_up(zi[n], 1, 64);
            zr[n] = l0 ? br : tr;
            zi[n] = l0 ? bi : ti;
        }
    }

    // ---- Phase 3: replay with incoming state; skip+GELU; bf16 store ----
    // store layout: gyb[((b*128 + (t*2+wv))*128 + h)*64 + lane], t=t4*4+j
    const float Dh = Dp[h];
    unsigned short* gb = gyb + (size_t)b * (128 * 128 * 64)
                             + (size_t)wv * 8192 + h * 64 + lane;
    const float4* xq = (const float4*)xb;
    float4 xa = xq[0], xbv = xq[1];
#pragma unroll 1
    for (int t4 = 0; t4 < T_ / 4; ++t4) {
        float4 na, nb;
        if (t4 < T_ / 4 - 1) { na = xq[2 * t4 + 2]; nb = xq[2 * t4 + 3]; }
        float u[4], p[4];
        u[0] = fmaf(xa.x, ew0, fmaf(xa.y, ew1, eb));
        u[1] = fmaf(xa.z, ew0, fmaf(xa.w, ew1, eb));
        u[2] = fmaf(xbv.x, ew0, fmaf(xbv.y, ew1, eb));
        u[3] = fmaf(xbv.z, ew0, fmaf(xbv.w, ew1, eb));
#pragma unroll
        for (int j = 0; j < 4; ++j) p[j] = 0.f;
#pragma unroll
        for (int ng = 0; ng < 8; ++ng) {
            float4 q[4];
#pragma unroll
            for (int m = 0; m < 4; ++m) q[m] = cw4[ng * 4 + m];
#pragma unroll
            for (int m = 0; m < 4; ++m) {
                int n = ng * 4 + m;
                float ar_ = zr[n], ai_ = zi[n];
#pragma unroll
                for (int j = 0; j < 4; ++j) {
                    float nr = fmaf(q[m].x, ar_, fmaf(-q[m].y, ai_, u[j]));
                    ai_ = fmaf(q[m].x, ai_, q[m].y * ar_);
                    ar_ = nr;
                    p[j] = fmaf(q[m].z, ar_, fmaf(-q[m].w, ai_, p[j]));
                }
                zr[n] = ar_; zi[n] = ai_;
            }
        }
#pragma unroll
        for (int j = 0; j < 4; ++j) {
            float y = fmaf(Dh, u[j], 2.f * p[j]);
            int t = t4 * 4 + j;
            gb[(size_t)t * 16384] = f2bf(gelu_tanh(y));
        }
        xa = na; xbv = nb;
    }
}

// ---------------------------------------------------------------------------
// k_mix: bf16 MFMA GLU mix + pooled decode -> per-block partial (NO atomics).
// One block per (b,T'): 64 l'-cols; C[g][v] = (Whi+Wlo)[g][h] x gy[h][v].
// ---------------------------------------------------------------------------
#define BPAD 136   // Bt row stride in ushorts (16B-aligned)
#define GPAD 66    // gate row stride in floats
__global__ __launch_bounds__(256) void k_mix(
    const unsigned short* __restrict__ Whi, const unsigned short* __restrict__ Wlo,
    const unsigned short* __restrict__ gyb, const float* __restrict__ out_b,
    const float* __restrict__ dec_w, float* __restrict__ part)
{
    __shared__ unsigned short Bt[64 * BPAD];   // [v][h] transposed gy tile
    __shared__ float gateL[128 * GPAD];        // sigmoid(z_gate)
    __shared__ float red[2];

    const int blk = blockIdx.x;                // = b*128 + T'
    const int tid = threadIdx.x;
    const int wq = tid >> 6, lane = tid & 63;

    // ---- stage gy slice (128h x 64v bf16, contiguous 16 KB) transposed ----
    const unsigned short* gys = gyb + (size_t)blk * 8192;
#pragma unroll
    for (int it = 0; it < 4; ++it) {
        int idx = it * 256 + tid;              // 0..1023
        int h = idx >> 3, v0 = (idx & 7) * 8;
        uint4 q = *(const uint4*)(gys + h * 64 + v0);
        Bt[(v0 + 0) * BPAD + h] = (unsigned short)(q.x & 0xFFFF);
        Bt[(v0 + 1) * BPAD + h] = (unsigned short)(q.x >> 16);
        Bt[(v0 + 2) * BPAD + h] = (unsigned short)(q.y & 0xFFFF);
        Bt[(v0 + 3) * BPAD + h] = (unsigned short)(q.y >> 16);
        Bt[(v0 + 4) * BPAD + h] = (unsigned short)(q.z & 0xFFFF);
        Bt[(v0 + 5) * BPAD + h] = (unsigned short)(q.z >> 16);
        Bt[(v0 + 6) * BPAD + h] = (unsigned short)(q.w & 0xFFFF);
        Bt[(v0 + 7) * BPAD + h] = (unsigned short)(q.w >> 16);
    }
    __syncthreads();

    // ---- MFMA K-loop: wave wq owns g-strip [64*wq, 64*wq+64) ----
    const int gbase = wq * 64;
    const int mrow = lane & 15;
    const int quad = lane >> 4;
    f32x4 acc[4][4];
#pragma unroll
    for (int mt = 0; mt < 4; ++mt)
#pragma unroll
        for (int nt = 0; nt < 4; ++nt)
            acc[mt][nt] = (f32x4){0.f, 0.f, 0.f, 0.f};

#pragma unroll
    for (int k = 0; k < 4; ++k) {
        const int h0 = k * 32 + quad * 8;
        short8 bfr[4];
#pragma unroll
        for (int nt = 0; nt < 4; ++nt) {
            int v = nt * 16 + mrow;
            bfr[nt] = *(const short8*)(Bt + v * BPAD + h0);
        }
#pragma unroll
        for (int mt = 0; mt < 4; ++mt) {
            int g = gbase + mt * 16 + mrow;
            short8 ah = *(const short8*)(Whi + g * 128 + h0);
            short8 al = *(const short8*)(Wlo + g * 128 + h0);
#pragma unroll
            for (int nt = 0; nt < 4; ++nt) {
                acc[mt][nt] = __builtin_amdgcn_mfma_f32_16x16x32_bf16(
                    ah, bfr[nt], acc[mt][nt], 0, 0, 0);
                acc[mt][nt] = __builtin_amdgcn_mfma_f32_16x16x32_bf16(
                    al, bfr[nt], acc[mt][nt], 0, 0, 0);
            }
        }
    }

    // ---- epilogue: C row g = gbase + mt*16 + quad*4 + r, col v = nt*16+mrow
    float4 ob[4];
#pragma unroll
    for (int mt = 0; mt < 4; ++mt)
        ob[mt] = *(const float4*)(out_b + gbase + mt * 16 + quad * 4);

    if (wq >= 2) {                             // gate waves: sigmoid -> LDS
#pragma unroll
        for (int mt = 0; mt < 4; ++mt) {
            int gL = (gbase - 128) + mt * 16 + quad * 4;
#pragma unroll
            for (int nt = 0; nt < 4; ++nt) {
                int v = nt * 16 + mrow;
#pragma unroll
                for (int r = 0; r < 4; ++r) {
                    float zg = acc[mt][nt][r] + ob[mt][r];
                    gateL[(gL + r) * GPAD + v] =
                        __fdividef(1.f, 1.f + __expf(-zg));
                }
            }
        }
    }
    __syncthreads();

    if (wq < 2) {                              // a waves: GLU + dec dot + pool
        float4 dv[4];
#pragma unroll
        for (int mt = 0; mt < 4; ++mt)
            dv[mt] = *(const float4*)(dec_w + gbase + mt * 16 + quad * 4);
        float s = 0.f;
#pragma unroll
        for (int mt = 0; mt < 4; ++mt) {
            int gL = gbase + mt * 16 + quad * 4;
#pragma unroll
            for (int nt = 0; nt < 4; ++nt) {
                int v = nt * 16 + mrow;
#pragma unroll
                for (int r = 0; r < 4; ++r) {
                    float a = acc[mt][nt][r] + ob[mt][r];
                    float sg = gateL[(gL + r) * GPAD + v];
                    s = fmaf(dv[mt][r], a * sg, s);
                }
            }
        }
#pragma unroll
        for (int off = 32; off; off >>= 1) s += __shfl_down(s, off, 64);
        if (lane == 0) red[wq] = s;
    }
    __syncthreads();
    if (tid == 0) part[blk] = red[0] + red[1];  // plain store, no atomic
}

// ---------------------------------------------------------------------------
// k_final: reduce 128 partials per batch; out[b] = dec_b + sum/L.
// ---------------------------------------------------------------------------
__global__ __launch_bounds__(512) void k_final(
    const float* __restrict__ part, const float* __restrict__ dec_b,
    float* __restrict__ out)
{
    int tid = threadIdx.x;
    int b = tid >> 6, lane = tid & 63;
    float s = part[b * 128 + lane] + part[b * 128 + 64 + lane];
#pragma unroll
    for (int off = 32; off; off >>= 1) s += __shfl_down(s, off, 64);
    if (lane == 0) out[b] = fmaf(s, 1.0f / (float)L_, dec_b[0]);
}

// ---------------------------------------------------------------------------
extern "C" void kernel_launch(void* const* d_in, const int* in_sizes, int n_in,
                              void* d_out, int out_size, void* d_ws, size_t ws_size,
                              hipStream_t stream)
{
    const float* x         = (const float*)d_in[0];
    const float* enc_w     = (const float*)d_in[1];
    const float* enc_b     = (const float*)d_in[2];
    const float* log_dt    = (const float*)d_in[3];
    const float* log_A_real= (const float*)d_in[4];
    const float* A_imag    = (const float*)d_in[5];
    const float* C_re      = (const float*)d_in[6];
    const float* C_im      = (const float*)d_in[7];
    const float* Dp        = (const float*)d_in[8];
    const float* out_w     = (const float*)d_in[9];
    const float* out_b     = (const float*)d_in[10];
    const float* dec_w     = (const float*)d_in[11];
    const float* dec_b     = (const float*)d_in[12];
    float* out = (float*)d_out;

    char* ws = (char*)d_ws;
    unsigned short* Whi = (unsigned short*)(ws);
    unsigned short* Wlo = (unsigned short*)(ws + 65536);
    unsigned short* gyb = (unsigned short*)(ws + 131072);
    float* part = (float*)(ws + 131072 + 16777216);

    k_setup<<<128, 256, 0, stream>>>(out_w, Whi, Wlo);
    k_s4d<<<B_ * H_, C_, 0, stream>>>(x, enc_w, enc_b, log_dt, log_A_real,
                                      A_imag, C_re, C_im, Dp, gyb);
    k_mix<<<B_ * 128, 256, 0, stream>>>(Whi, Wlo, gyb, out_b, dec_w, part);
    k_final<<<1, 512, 0, stream>>>(part, dec_b, out);
}

// Round 8
// 184.855 us; speedup vs baseline: 1.0545x; 1.0545x over previous
//
#include <hip/hip_runtime.h>
#include <math.h>

// Problem dims (fixed by the reference)
#define B_ 8
#define L_ 8192
#define H_ 128
#define N_ 32
#define C_ 128   // chunks along L (= threads per k_s4d block)
#define T_ 64    // chunk length (C_*T_ == L_)

// ws layout:
//   Wh  ushort[256*128] @ 0        (64 KB)  fp16 out_w, [g][h] (MFMA A layout)
//   gy  float[B_*H_*L_] @ 65536    (32 MB)  fp32 gy, [b][h][l'], l' = t*128+c
//   part float[1024]    @ 33619968 (4 KB)   per-block k_mix partials
// l' = t*C_+c is a fixed permutation of l; mix+pool is order-invariant.

typedef __attribute__((ext_vector_type(8))) short short8;
typedef _Float16 half8 __attribute__((ext_vector_type(8)));
typedef __attribute__((ext_vector_type(4))) float f32x4;

__device__ __forceinline__ float gelu_tanh(float y) {
    float t = 0.7978845608028654f * fmaf(0.044715f, y * y * y, y);
    float e = __expf(2.f * t);
    float th = 1.f - __fdividef(2.f, e + 1.f);
    return 0.5f * y * (1.f + th);
}

// ---------------------------------------------------------------------------
// k_s4d: fused encoder + chunked S4D scan + skip + GELU -> fp32 gy (EXACT R4
// structure: 98us proven). Side task: each block converts 32 out_w -> fp16.
// PLAIN __launch_bounds__(128): min-wave bounds spill (R3: 7x, R5: 1.5x).
// Phase-1 u-tile = 16 (R6 tile=8 lost ILP: 98->128us).
// ---------------------------------------------------------------------------
__global__ __launch_bounds__(128) void k_s4d(
    const float* __restrict__ x, const float* __restrict__ enc_w,
    const float* __restrict__ enc_b, const float* __restrict__ log_dt,
    const float* __restrict__ log_A_real, const float* __restrict__ A_imag,
    const float* __restrict__ C_re, const float* __restrict__ C_im,
    const float* __restrict__ Dp, const float* __restrict__ out_w,
    unsigned short* __restrict__ Wh, float* __restrict__ gy)
{
    const int bh = blockIdx.x;
    const int b = bh >> 7, h = bh & (H_ - 1);
    const int c = threadIdx.x;
    const int lane = c & 63, wv = c >> 6;

    __shared__ float4 cw4[N_];        // (wr, wi, coef_r, coef_i)
    __shared__ float4 pw[N_];         // (w2r, w2i, wr, wi)
    __shared__ float2 wTpow[7][N_];   // wT^(2^k)
    __shared__ float2 Sx[N_][64];     // wave-0 inclusive scans (16 KB)

    if (c < N_) {
        int idx = h * N_ + c;
        float dt = expf(log_dt[h]);
        float Ar = -expf(log_A_real[idx]);
        float Ai = A_imag[idx];
        float ar = dt * Ar, ai = dt * Ai;
        float er = expf(ar);
        float wr = er * cosf(ai), wi = er * sinf(ai);
        float numr = wr - 1.f, numi = wi;
        float inv = 1.f / (Ar * Ar + Ai * Ai);
        float qr = (numr * Ar + numi * Ai) * inv;
        float qi = (numi * Ar - numr * Ai) * inv;
        cw4[c] = make_float4(wr, wi, C_re[idx] * qr - C_im[idx] * qi,
                                     C_re[idx] * qi + C_im[idx] * qr);
        pw[c] = make_float4(wr * wr - wi * wi, 2.f * wr * wi, wr, wi);
        float erT = expf(ar * (float)T_);
        float pr = erT * cosf(ai * (float)T_), pi = erT * sinf(ai * (float)T_);
#pragma unroll
        for (int k = 0; k < 7; ++k) {
            wTpow[k][c] = make_float2(pr, pi);
            float nr = pr * pr - pi * pi;
            pi = 2.f * pr * pi; pr = nr;
        }
        // side task: convert this block's 32-element slice of out_w to fp16
        int widx = bh * 32 + c;
        _Float16 hv = (_Float16)out_w[widx];
        Wh[widx] = *(unsigned short*)&hv;
    }
    __syncthreads();

    const float2* xb = (const float2*)x + (size_t)b * L_ + c * T_;
    const float ew0 = enc_w[h], ew1 = enc_w[H_ + h], eb = enc_b[h];

    // ---- Phase 1: E[c] via w^2 double-steps; 16-timestep u tile, n by 4 ----
    float zr[N_], zi[N_];
#pragma unroll
    for (int n = 0; n < N_; ++n) { zr[n] = 0.f; zi[n] = 0.f; }

#pragma unroll 1
    for (int tt = 0; tt < T_ / 16; ++tt) {      // 4 tiles of 16 timesteps
        float u[16];
        const float4* xq = (const float4*)xb + tt * 8;
#pragma unroll
        for (int j = 0; j < 8; ++j) {
            float4 xv = xq[j];
            u[2 * j]     = fmaf(xv.x, ew0, fmaf(xv.y, ew1, eb));
            u[2 * j + 1] = fmaf(xv.z, ew0, fmaf(xv.w, ew1, eb));
        }
#pragma unroll
        for (int ng = 0; ng < 8; ++ng) {
            float4 q[4];
#pragma unroll
            for (int m = 0; m < 4; ++m) q[m] = pw[ng * 4 + m];
#pragma unroll
            for (int m = 0; m < 4; ++m) {
                int n = ng * 4 + m;
                float ar_ = zr[n], ai_ = zi[n];
#pragma unroll
                for (int t2 = 0; t2 < 8; ++t2) {
                    float ua = u[2 * t2], ub = u[2 * t2 + 1];
                    float mr = fmaf(q[m].z, ua, ub);
                    float mi = q[m].w * ua;
                    float nr = fmaf(q[m].x, ar_, fmaf(-q[m].y, ai_, mr));
                    ai_ = fmaf(q[m].x, ai_, fmaf(q[m].y, ar_, mi));
                    ar_ = nr;
                }
                zr[n] = ar_; zi[n] = ai_;
            }
        }
    }

    // ---- Phase 2: scan over chunks ----
#pragma unroll
    for (int k = 0; k < 6; ++k) {
        int s = 1 << k;
        float mask = (lane >= s) ? 1.f : 0.f;
#pragma unroll
        for (int n = 0; n < N_; ++n) {
            float2 q = wTpow[k][n];
            float vr = __shfl_up(zr[n], s, 64);
            float vi = __shfl_up(zi[n], s, 64);
            float adr = fmaf(q.x, vr, -(q.y * vi));
            float adi = fmaf(q.x, vi, q.y * vr);
            zr[n] = fmaf(mask, adr, zr[n]);
            zi[n] = fmaf(mask, adi, zi[n]);
        }
    }
    if (wv == 0) {
#pragma unroll
        for (int n = 0; n < N_; ++n) Sx[n][lane] = make_float2(zr[n], zi[n]);
    }
    __syncthreads();
    if (wv == 1) {
#pragma unroll
        for (int n = 0; n < N_; ++n) {
            float2 q = wTpow[6][n];
            float2 v = Sx[n][lane];
            zr[n] = fmaf(q.x, v.x, fmaf(-q.y, v.y, zr[n]));
            zi[n] = fmaf(q.x, v.y, fmaf(q.y, v.x, zi[n]));
        }
    }
    {
        bool l0 = (lane == 0);
#pragma unroll
        for (int n = 0; n < N_; ++n) {
            float2 bv = Sx[n][63];
            float br = (wv == 1) ? bv.x : 0.f;
            float bi = (wv == 1) ? bv.y : 0.f;
            float tr = __shfl_up(zr[n], 1, 64);
            float ti = __shfl_up(zi[n], 1, 64);
            zr[n] = l0 ? br : tr;
            zi[n] = l0 ? bi : ti;
        }
    }

    // ---- Phase 3: replay with incoming state; skip+GELU; fp32 store ----
    // store layout (R4): gy[(b*128+h)*8192 + t*128 + c]  (block-private 32KB)
    const float Dh = Dp[h];
    float* gyp = gy + (size_t)(b * H_ + h) * L_ + c;
    const float4* xq = (const float4*)xb;
    float4 xa = xq[0], xbv = xq[1];
#pragma unroll 1
    for (int t4 = 0; t4 < T_ / 4; ++t4) {
        float4 na, nb;
        if (t4 < T_ / 4 - 1) { na = xq[2 * t4 + 2]; nb = xq[2 * t4 + 3]; }
        float u[4], p[4];
        u[0] = fmaf(xa.x, ew0, fmaf(xa.y, ew1, eb));
        u[1] = fmaf(xa.z, ew0, fmaf(xa.w, ew1, eb));
        u[2] = fmaf(xbv.x, ew0, fmaf(xbv.y, ew1, eb));
        u[3] = fmaf(xbv.z, ew0, fmaf(xbv.w, ew1, eb));
#pragma unroll
        for (int j = 0; j < 4; ++j) p[j] = 0.f;
#pragma unroll
        for (int ng = 0; ng < 8; ++ng) {
            float4 q[4];
#pragma unroll
            for (int m = 0; m < 4; ++m) q[m] = cw4[ng * 4 + m];
#pragma unroll
            for (int m = 0; m < 4; ++m) {
                int n = ng * 4 + m;
                float ar_ = zr[n], ai_ = zi[n];
#pragma unroll
                for (int j = 0; j < 4; ++j) {
                    float nr = fmaf(q[m].x, ar_, fmaf(-q[m].y, ai_, u[j]));
                    ai_ = fmaf(q[m].x, ai_, q[m].y * ar_);
                    ar_ = nr;
                    p[j] = fmaf(q[m].z, ar_, fmaf(-q[m].w, ai_, p[j]));
                }
                zr[n] = ar_; zi[n] = ai_;
            }
        }
#pragma unroll
        for (int j = 0; j < 4; ++j) {
            float y = fmaf(Dh, u[j], 2.f * p[j]);
            gyp[(size_t)(t4 * 4 + j) * C_] = gelu_tanh(y);
        }
        xa = na; xbv = nb;
    }
}

// ---------------------------------------------------------------------------
// k_mix: fp16 MFMA GLU mix + pooled decode -> per-block partial (no atomics).
// Block = (b, t, c-half): 64 l'-columns. C[g][v] = Wh[g][h] x gy_f16[h][v].
// Single fp16 W (no hi/lo): 64 MFMA/wave. Gate exchange via lane-linear LDS.
// ---------------------------------------------------------------------------
#define BPAD 136   // Bt row stride in ushorts (16B-aligned)
__global__ __launch_bounds__(256) void k_mix(
    const unsigned short* __restrict__ Wh, const float* __restrict__ gy,
    const float* __restrict__ out_b, const float* __restrict__ dec_w,
    float* __restrict__ part)
{
    __shared__ unsigned short Bt[64 * BPAD];   // [v][h] fp16 transposed tile
    __shared__ float gx[2 * 4096];             // gate sigmoids, lane-linear
    __shared__ float red[2];

    const int blk = blockIdx.x;                // = b*128 + t*2 + ch
    const int b = blk >> 7;
    const int t = (blk >> 1) & 63, ch = blk & 1;
    const int tid = threadIdx.x;
    const int wq = tid >> 6, lane = tid & 63;

    // ---- stage: read 128h x 64v fp32 tile, convert fp16, transpose ----
    const float* gsrc = gy + (size_t)(b * H_) * L_ + t * 128 + ch * 64;
#pragma unroll
    for (int it = 0; it < 8; ++it) {
        int idx = it * 256 + tid;              // 0..2047 float4-slots
        int h = idx >> 4, v0 = (idx & 15) * 4;
        float4 f = *(const float4*)(gsrc + (size_t)h * L_ + v0);
        _Float16 h0 = (_Float16)f.x, h1 = (_Float16)f.y,
                 h2 = (_Float16)f.z, h3 = (_Float16)f.w;
        Bt[(v0 + 0) * BPAD + h] = *(unsigned short*)&h0;
        Bt[(v0 + 1) * BPAD + h] = *(unsigned short*)&h1;
        Bt[(v0 + 2) * BPAD + h] = *(unsigned short*)&h2;
        Bt[(v0 + 3) * BPAD + h] = *(unsigned short*)&h3;
    }
    __syncthreads();

    // ---- MFMA K-loop: wave wq owns g-strip [64*wq, 64*wq+64) ----
    const int gbase = wq * 64;
    const int mrow = lane & 15;
    const int quad = lane >> 4;
    f32x4 acc[4][4];
#pragma unroll
    for (int mt = 0; mt < 4; ++mt)
#pragma unroll
        for (int nt = 0; nt < 4; ++nt)
            acc[mt][nt] = (f32x4){0.f, 0.f, 0.f, 0.f};

#pragma unroll
    for (int k = 0; k < 4; ++k) {
        const int h0 = k * 32 + quad * 8;
        half8 bfr[4];
#pragma unroll
        for (int nt = 0; nt < 4; ++nt) {
            int v = nt * 16 + mrow;
            bfr[nt] = *(const half8*)(Bt + v * BPAD + h0);
        }
#pragma unroll
        for (int mt = 0; mt < 4; ++mt) {
            int g = gbase + mt * 16 + mrow;
            half8 ah = *(const half8*)(Wh + g * 128 + h0);
#pragma unroll
            for (int nt = 0; nt < 4; ++nt) {
                acc[mt][nt] = __builtin_amdgcn_mfma_f32_16x16x32_f16(
                    ah, bfr[nt], acc[mt][nt], 0, 0, 0);
            }
        }
    }

    // ---- epilogue: C row g = gbase + mt*16 + quad*4 + r, col v = nt*16+mrow
    float4 ob[4];
#pragma unroll
    for (int mt = 0; mt < 4; ++mt)
        ob[mt] = *(const float4*)(out_b + gbase + mt * 16 + quad * 4);

    if (wq >= 2) {                             // gate waves: sigmoid -> LDS
        float* gxw = gx + (wq - 2) * 4096;
#pragma unroll
        for (int mt = 0; mt < 4; ++mt) {
#pragma unroll
            for (int nt = 0; nt < 4; ++nt) {
#pragma unroll
                for (int r = 0; r < 4; ++r) {
                    float zg = acc[mt][nt][r] + ob[mt][r];
                    gxw[((mt * 4 + nt) * 4 + r) * 64 + lane] =
                        __fdividef(1.f, 1.f + __expf(-zg));
                }
            }
        }
    }
    __syncthreads();

    if (wq < 2) {                              // a waves: GLU + dec dot + pool
        const float* gxw = gx + wq * 4096;
        float4 dv[4];
#pragma unroll
        for (int mt = 0; mt < 4; ++mt)
            dv[mt] = *(const float4*)(dec_w + gbase + mt * 16 + quad * 4);
        float s = 0.f;
#pragma unroll
        for (int mt = 0; mt < 4; ++mt) {
#pragma unroll
            for (int nt = 0; nt < 4; ++nt) {
#pragma unroll
                for (int r = 0; r < 4; ++r) {
                    float a = acc[mt][nt][r] + ob[mt][r];
                    float sg = gxw[((mt * 4 + nt) * 4 + r) * 64 + lane];
                    s = fmaf(dv[mt][r], a * sg, s);
                }
            }
        }
#pragma unroll
        for (int off = 32; off; off >>= 1) s += __shfl_down(s, off, 64);
        if (lane == 0) red[wq] = s;
    }
    __syncthreads();
    if (tid == 0) part[blk] = red[0] + red[1];  // plain store, no atomic
}

// ---------------------------------------------------------------------------
// k_final: reduce 128 partials per batch; out[b] = dec_b + sum/L.
// ---------------------------------------------------------------------------
__global__ __launch_bounds__(512) void k_final(
    const float* __restrict__ part, const float* __restrict__ dec_b,
    float* __restrict__ out)
{
    int tid = threadIdx.x;
    int b = tid >> 6, lane = tid & 63;
    float s = part[b * 128 + lane] + part[b * 128 + 64 + lane];
#pragma unroll
    for (int off = 32; off; off >>= 1) s += __shfl_down(s, off, 64);
    if (lane == 0) out[b] = fmaf(s, 1.0f / (float)L_, dec_b[0]);
}

// ---------------------------------------------------------------------------
extern "C" void kernel_launch(void* const* d_in, const int* in_sizes, int n_in,
                              void* d_out, int out_size, void* d_ws, size_t ws_size,
                              hipStream_t stream)
{
    const float* x         = (const float*)d_in[0];
    const float* enc_w     = (const float*)d_in[1];
    const float* enc_b     = (const float*)d_in[2];
    const float* log_dt    = (const float*)d_in[3];
    const float* log_A_real= (const float*)d_in[4];
    const float* A_imag    = (const float*)d_in[5];
    const float* C_re      = (const float*)d_in[6];
    const float* C_im      = (const float*)d_in[7];
    const float* Dp        = (const float*)d_in[8];
    const float* out_w     = (const float*)d_in[9];
    const float* out_b     = (const float*)d_in[10];
    const float* dec_w     = (const float*)d_in[11];
    const float* dec_b     = (const float*)d_in[12];
    float* out = (float*)d_out;

    char* ws = (char*)d_ws;
    unsigned short* Wh = (unsigned short*)(ws);
    float* gy   = (float*)(ws + 65536);
    float* part = (float*)(ws + 65536 + 33554432);

    k_s4d<<<B_ * H_, C_, 0, stream>>>(x, enc_w, enc_b, log_dt, log_A_real,
                                      A_imag, C_re, C_im, Dp, out_w, Wh, gy);
    k_mix<<<B_ * 128, 256, 0, stream>>>(Wh, gy, out_b, dec_w, part);
    k_final<<<1, 512, 0, stream>>>(part, dec_b, out);
}

// Round 10
// 178.651 us; speedup vs baseline: 1.0911x; 1.0347x over previous
//
#include <hip/hip_runtime.h>
#include <math.h>

// Problem dims (fixed by the reference)
#define B_ 8
#define L_ 8192
#define H_ 128
#define N_ 32
#define C_ 128   // chunks along L
#define T_ 64    // chunk length

// ws layout:
//   Wh   ushort[256*128]     @ 0        (64 KB)  fp16 out_w [g][h]
//   Kh   ushort[128*64*64]   @ 65536    (1 MB)   fp16 Klo[h][t][j] (Toeplitz)
//   Ph   ushort[128*64*64]   @ 1114112  (1 MB)   fp16 P[h][t][m']  (state inj)
//   Vh   ushort[128*64*64]   @ 2162688  (1 MB)   fp16 V[h][m'][j]  (Vandermonde)
//   gy   float[B_*H_*L_]     @ 3211264  (32 MB)  fp32 gy [b][h][l'], l'=t*128+c
//   part float[1024]         @ 36765696 (4 KB)

typedef _Float16 half8 __attribute__((ext_vector_type(8)));
typedef __attribute__((ext_vector_type(4))) float f32x4;

__device__ __forceinline__ float gelu_tanh(float y) {
    float t = 0.7978845608028654f * fmaf(0.044715f, y * y * y, y);
    float e = __expf(2.f * t);
    float th = 1.f - __fdividef(2.f, e + 1.f);
    return 0.5f * y * (1.f + th);
}
__device__ __forceinline__ unsigned short f2h(float f) {
    _Float16 h = (_Float16)f;
    return *(unsigned short*)&h;
}

// ---------------------------------------------------------------------------
// k_prep: per-h fp16 matrices Klo/P/V + Wh (out_w fp16). Block = h.
//   Klo[t][j] = K[t-j] (t>=j), K[d] = 2*Re sum_n coef_n w_n^d
//   P[t][n] = 2Re(coef_n w^{t+1}); P[t][32+n] = -2Im(coef_n w^{t+1})
//   V[n][j] = Re(w^{63-j});        V[32+n][j] = Im(w^{63-j})
// ---------------------------------------------------------------------------
__global__ __launch_bounds__(256) void k_prep(
    const float* __restrict__ log_dt, const float* __restrict__ log_A_real,
    const float* __restrict__ A_imag, const float* __restrict__ C_re,
    const float* __restrict__ C_im, const float* __restrict__ out_w,
    unsigned short* __restrict__ Wh, unsigned short* __restrict__ Kh,
    unsigned short* __restrict__ Ph, unsigned short* __restrict__ Vh)
{
    const int h = blockIdx.x;
    const int tid = threadIdx.x;
    __shared__ float2 wtab[65][N_];
    __shared__ float2 coefs[N_];
    __shared__ float Kd[64];

    float dt = expf(log_dt[h]);
#pragma unroll
    for (int it = 0; it < 9; ++it) {
        int idx = it * 256 + tid;
        if (idx < 65 * N_) {
            int d = idx >> 5, n = idx & 31;
            float Ar = -expf(log_A_real[h * N_ + n]);
            float Ai = A_imag[h * N_ + n];
            float ar = dt * Ar * (float)d, ai = dt * Ai * (float)d;
            float er = expf(ar);
            wtab[d][n] = make_float2(er * cosf(ai), er * sinf(ai));
        }
    }
    if (tid < N_) {
        int n = tid;
        float Ar = -expf(log_A_real[h * N_ + n]);
        float Ai = A_imag[h * N_ + n];
        float ar = dt * Ar, ai = dt * Ai;
        float er = expf(ar);
        float wr = er * cosf(ai), wi = er * sinf(ai);
        float inv = 1.f / (Ar * Ar + Ai * Ai);
        float numr = wr - 1.f, numi = wi;
        float qr = (numr * Ar + numi * Ai) * inv;
        float qi = (numi * Ar - numr * Ai) * inv;
        coefs[n] = make_float2(C_re[h * N_ + n] * qr - C_im[h * N_ + n] * qi,
                               C_re[h * N_ + n] * qi + C_im[h * N_ + n] * qr);
    }
    __syncthreads();
    if (tid < 64) {
        float s = 0.f;
#pragma unroll
        for (int n = 0; n < N_; ++n) {
            float2 cf = coefs[n]; float2 w = wtab[tid][n];
            s += cf.x * w.x - cf.y * w.y;
        }
        Kd[tid] = 2.f * s;
    }
    __syncthreads();
#pragma unroll
    for (int it = 0; it < 16; ++it) {
        int idx = it * 256 + tid;              // t*64 + j
        int t = idx >> 6, j = idx & 63;
        Kh[h * 4096 + idx] = f2h((t >= j) ? Kd[t - j] : 0.f);
    }
#pragma unroll
    for (int it = 0; it < 16; ++it) {
        int idx = it * 256 + tid;              // t*64 + m
        int t = idx >> 6, m = idx & 63, n = m & 31;
        float2 cf = coefs[n]; float2 w = wtab[t + 1][n];
        float re = cf.x * w.x - cf.y * w.y;
        float im = cf.x * w.y + cf.y * w.x;
        Ph[h * 4096 + idx] = f2h((m < 32) ? 2.f * re : -2.f * im);
    }
#pragma unroll
    for (int it = 0; it < 16; ++it) {
        int idx = it * 256 + tid;              // m*64 + j
        int m = idx >> 6, j = idx & 63, n = m & 31;
        float2 w = wtab[63 - j][n];
        Vh[h * 4096 + idx] = f2h((m < 32) ? w.x : w.y);
    }
    {   // out_w rows g = 2h, 2h+1 -> fp16
        int g = 2 * h + (tid >> 7), j = tid & 127;
        Wh[g * 128 + j] = f2h(out_w[g * 128 + j]);
    }
}

// ---------------------------------------------------------------------------
// k_s4d: MFMA-Toeplitz S4D. Block = (b,h), 256 threads (4 waves).
//   stage u (fp16, LDS Ut[c][j]; 16 float4 loads/thread — R9's 8 left half
//   of Ut uninitialized -> NaN) -> E = V@U (MFMA) -> shuffle scan (R4-proven)
//   -> S (fp16 LDS, aliases E32) -> Y = Klo@U + P@S (MFMA) -> epilogue
//   y + D*u, GELU, fp32 gy store (R4-proven layout).
// ---------------------------------------------------------------------------
__global__ __launch_bounds__(256) void k_s4d(
    const float* __restrict__ x, const float* __restrict__ enc_w,
    const float* __restrict__ enc_b, const float* __restrict__ log_dt,
    const float* __restrict__ log_A_real, const float* __restrict__ A_imag,
    const float* __restrict__ Dp, const unsigned short* __restrict__ Kh,
    const unsigned short* __restrict__ Ph, const unsigned short* __restrict__ Vh,
    float* __restrict__ gy)
{
    const int bh = blockIdx.x;
    const int b = bh >> 7, h = bh & (H_ - 1);
    const int tid = threadIdx.x;
    const int lane = tid & 63, wq = tid >> 6;
    const int mrow = lane & 15, quad = lane >> 4;

    __shared__ unsigned short Ut[C_][72];   // [c][j] fp16 u  (18.4 KB)
    __shared__ float E32[64 * 130];         // E scratch (33.3 KB), reused as St
    __shared__ float2 Sx[N_][64];           // scan handoff (16 KB)
    __shared__ float2 wTpow[7][N_];
    unsigned short* St = (unsigned short*)E32;  // [c][m'] fp16, stride 72

    if (tid < N_) {
        int idx = h * N_ + tid;
        float dt = expf(log_dt[h]);
        float Ar = -expf(log_A_real[idx]);
        float Ai = A_imag[idx];
        float ar = dt * Ar * (float)T_, ai = dt * Ai * (float)T_;
        float er = expf(ar);
        float pr = er * cosf(ai), pi = er * sinf(ai);
#pragma unroll
        for (int k = 0; k < 7; ++k) {
            wTpow[k][tid] = make_float2(pr, pi);
            float nr = pr * pr - pi * pi;
            pi = 2.f * pr * pi; pr = nr;
        }
    }

    // ---- stage: u = enc(x) -> Ut[c][j] fp16 (16 float4 = 32 timesteps) ----
    const float ew0 = enc_w[h], ew1 = enc_w[H_ + h], eb = enc_b[h];
    {
        int c = tid >> 1, j0 = (tid & 1) * 32;
        const float4* xp = (const float4*)((const float2*)x + (size_t)b * L_
                                           + c * 64 + j0);
#pragma unroll
        for (int i = 0; i < 16; ++i) {
            float4 xv = xp[i];
            float u0 = fmaf(xv.x, ew0, fmaf(xv.y, ew1, eb));
            float u1 = fmaf(xv.z, ew0, fmaf(xv.w, ew1, eb));
            unsigned int pk = (unsigned)f2h(u0) | ((unsigned)f2h(u1) << 16);
            *(unsigned int*)&Ut[c][j0 + 2 * i] = pk;
        }
    }
    __syncthreads();

    // ---- GEMM E[m 64][c 128] = V[m][j] @ U[j][c]; wave wq -> m-tile wq ----
    {
        f32x4 acc[8];
#pragma unroll
        for (int nt = 0; nt < 8; ++nt) acc[nt] = (f32x4){0.f, 0.f, 0.f, 0.f};
        const unsigned short* Arow = Vh + h * 4096 + (wq * 16 + mrow) * 64;
#pragma unroll
        for (int ks = 0; ks < 2; ++ks) {
            int k0 = ks * 32 + quad * 8;
            half8 af = *(const half8*)(Arow + k0);
#pragma unroll
            for (int nt = 0; nt < 8; ++nt) {
                half8 bf = *(const half8*)&Ut[nt * 16 + mrow][k0];
                acc[nt] = __builtin_amdgcn_mfma_f32_16x16x32_f16(
                    af, bf, acc[nt], 0, 0, 0);
            }
        }
#pragma unroll
        for (int nt = 0; nt < 8; ++nt) {
            int cc = nt * 16 + mrow;
#pragma unroll
            for (int r = 0; r < 4; ++r)
                E32[(wq * 16 + quad * 4 + r) * 130 + cc] = acc[nt][r];
        }
    }
    __syncthreads();

    // ---- scan over chunks (threads 0..127; R4-proven structure) ----
    float zr[N_], zi[N_];
    const int sl = tid & 63, wv = (tid >> 6) & 1;
    if (tid < 128) {
        int c = tid;
#pragma unroll
        for (int n = 0; n < N_; ++n) {
            zr[n] = E32[n * 130 + c];
            zi[n] = E32[(32 + n) * 130 + c];
        }
#pragma unroll
        for (int k = 0; k < 6; ++k) {
            int s = 1 << k;
            float mask = (sl >= s) ? 1.f : 0.f;
#pragma unroll
            for (int n = 0; n < N_; ++n) {
                float2 q = wTpow[k][n];
                float vr = __shfl_up(zr[n], s, 64);
                float vi = __shfl_up(zi[n], s, 64);
                float adr = fmaf(q.x, vr, -(q.y * vi));
                float adi = fmaf(q.x, vi, q.y * vr);
                zr[n] = fmaf(mask, adr, zr[n]);
                zi[n] = fmaf(mask, adi, zi[n]);
            }
        }
        if (wv == 0) {
#pragma unroll
            for (int n = 0; n < N_; ++n) Sx[n][sl] = make_float2(zr[n], zi[n]);
        }
    }
    __syncthreads();
    if (tid < 128) {
        if (wv == 1) {
#pragma unroll
            for (int n = 0; n < N_; ++n) {
                float2 q = wTpow[6][n];
                float2 v = Sx[n][sl];
                zr[n] = fmaf(q.x, v.x, fmaf(-q.y, v.y, zr[n]));
                zi[n] = fmaf(q.x, v.y, fmaf(q.y, v.x, zi[n]));
            }
        }
        bool l0 = (sl == 0);
#pragma unroll
        for (int n = 0; n < N_; ++n) {
            float2 bv = Sx[n][63];
            float br = (wv == 1) ? bv.x : 0.f;
            float bi = (wv == 1) ? bv.y : 0.f;
            float tr = __shfl_up(zr[n], 1, 64);
            float ti = __shfl_up(zi[n], 1, 64);
            zr[n] = l0 ? br : tr;
            zi[n] = l0 ? bi : ti;
        }
        // write S (fp16, aliases E32 region; all E32 reads completed above)
        int c = tid;
#pragma unroll
        for (int n2 = 0; n2 < 16; ++n2) {
            unsigned int p0 = (unsigned)f2h(zr[2 * n2]) |
                              ((unsigned)f2h(zr[2 * n2 + 1]) << 16);
            unsigned int p1 = (unsigned)f2h(zi[2 * n2]) |
                              ((unsigned)f2h(zi[2 * n2 + 1]) << 16);
            *(unsigned int*)&St[c * 72 + 2 * n2] = p0;
            *(unsigned int*)&St[c * 72 + 32 + 2 * n2] = p1;
        }
    }
    __syncthreads();

    // ---- GEMM Y[t][c] = Klo@U + P@S; wave wq -> t-tile wq; epilogue ----
    {
        f32x4 acc[8];
#pragma unroll
        for (int nt = 0; nt < 8; ++nt) acc[nt] = (f32x4){0.f, 0.f, 0.f, 0.f};
        const unsigned short* Krow = Kh + h * 4096 + (wq * 16 + mrow) * 64;
#pragma unroll
        for (int ks = 0; ks < 2; ++ks) {
            int k0 = ks * 32 + quad * 8;
            half8 af = *(const half8*)(Krow + k0);
#pragma unroll
            for (int nt = 0; nt < 8; ++nt) {
                half8 bf = *(const half8*)&Ut[nt * 16 + mrow][k0];
                acc[nt] = __builtin_amdgcn_mfma_f32_16x16x32_f16(
                    af, bf, acc[nt], 0, 0, 0);
            }
        }
        const unsigned short* Prow = Ph + h * 4096 + (wq * 16 + mrow) * 64;
#pragma unroll
        for (int ks = 0; ks < 2; ++ks) {
            int k0 = ks * 32 + quad * 8;
            half8 af = *(const half8*)(Prow + k0);
#pragma unroll
            for (int nt = 0; nt < 8; ++nt) {
                half8 bf = *(const half8*)&St[(nt * 16 + mrow) * 72 + k0];
                acc[nt] = __builtin_amdgcn_mfma_f32_16x16x32_f16(
                    af, bf, acc[nt], 0, 0, 0);
            }
        }
        const float Dh = Dp[h];
        float* gyb = gy + (size_t)bh * L_;
        const float2* xb2 = (const float2*)x + (size_t)b * L_;
#pragma unroll
        for (int nt = 0; nt < 8; ++nt) {
            int c = nt * 16 + mrow;
#pragma unroll
            for (int r = 0; r < 4; ++r) {
                int t = wq * 16 + quad * 4 + r;
                float2 xv = xb2[c * 64 + t];
                float u = fmaf(xv.x, ew0, fmaf(xv.y, ew1, eb));
                float y = fmaf(Dh, u, acc[nt][r]);
                gyb[t * 128 + c] = gelu_tanh(y);
            }
        }
    }
}

// ---------------------------------------------------------------------------
// k_mix: fp16 MFMA GLU mix + pooled decode (UNCHANGED from R8 — isolate).
// ---------------------------------------------------------------------------
#define BPAD 136
__global__ __launch_bounds__(256) void k_mix(
    const unsigned short* __restrict__ Wh, const float* __restrict__ gy,
    const float* __restrict__ out_b, const float* __restrict__ dec_w,
    float* __restrict__ part)
{
    __shared__ unsigned short Bt[64 * BPAD];
    __shared__ float gx[2 * 4096];
    __shared__ float red[2];

    const int blk = blockIdx.x;                // = b*128 + t*2 + ch
    const int b = blk >> 7;
    const int t = (blk >> 1) & 63, ch = blk & 1;
    const int tid = threadIdx.x;
    const int wq = tid >> 6, lane = tid & 63;

    const float* gsrc = gy + (size_t)(b * H_) * L_ + t * 128 + ch * 64;
#pragma unroll
    for (int it = 0; it < 8; ++it) {
        int idx = it * 256 + tid;
        int h = idx >> 4, v0 = (idx & 15) * 4;
        float4 f = *(const float4*)(gsrc + (size_t)h * L_ + v0);
        Bt[(v0 + 0) * BPAD + h] = f2h(f.x);
        Bt[(v0 + 1) * BPAD + h] = f2h(f.y);
        Bt[(v0 + 2) * BPAD + h] = f2h(f.z);
        Bt[(v0 + 3) * BPAD + h] = f2h(f.w);
    }
    __syncthreads();

    const int gbase = wq * 64;
    const int mrow = lane & 15;
    const int quad = lane >> 4;
    f32x4 acc[4][4];
#pragma unroll
    for (int mt = 0; mt < 4; ++mt)
#pragma unroll
        for (int nt = 0; nt < 4; ++nt)
            acc[mt][nt] = (f32x4){0.f, 0.f, 0.f, 0.f};

#pragma unroll
    for (int k = 0; k < 4; ++k) {
        const int h0 = k * 32 + quad * 8;
        half8 bfr[4];
#pragma unroll
        for (int nt = 0; nt < 4; ++nt) {
            int v = nt * 16 + mrow;
            bfr[nt] = *(const half8*)(Bt + v * BPAD + h0);
        }
#pragma unroll
        for (int mt = 0; mt < 4; ++mt) {
            int g = gbase + mt * 16 + mrow;
            half8 ah = *(const half8*)(Wh + g * 128 + h0);
#pragma unroll
            for (int nt = 0; nt < 4; ++nt) {
                acc[mt][nt] = __builtin_amdgcn_mfma_f32_16x16x32_f16(
                    ah, bfr[nt], acc[mt][nt], 0, 0, 0);
            }
        }
    }

    float4 ob[4];
#pragma unroll
    for (int mt = 0; mt < 4; ++mt)
        ob[mt] = *(const float4*)(out_b + gbase + mt * 16 + quad * 4);

    if (wq >= 2) {
        float* gxw = gx + (wq - 2) * 4096;
#pragma unroll
        for (int mt = 0; mt < 4; ++mt)
#pragma unroll
            for (int nt = 0; nt < 4; ++nt)
#pragma unroll
                for (int r = 0; r < 4; ++r) {
                    float zg = acc[mt][nt][r] + ob[mt][r];
                    gxw[((mt * 4 + nt) * 4 + r) * 64 + lane] =
                        __fdividef(1.f, 1.f + __expf(-zg));
                }
    }
    __syncthreads();

    if (wq < 2) {
        const float* gxw = gx + wq * 4096;
        float4 dv[4];
#pragma unroll
        for (int mt = 0; mt < 4; ++mt)
            dv[mt] = *(const float4*)(dec_w + gbase + mt * 16 + quad * 4);
        float s = 0.f;
#pragma unroll
        for (int mt = 0; mt < 4; ++mt)
#pragma unroll
            for (int nt = 0; nt < 4; ++nt)
#pragma unroll
                for (int r = 0; r < 4; ++r) {
                    float a = acc[mt][nt][r] + ob[mt][r];
                    float sg = gxw[((mt * 4 + nt) * 4 + r) * 64 + lane];
                    s = fmaf(dv[mt][r], a * sg, s);
                }
#pragma unroll
        for (int off = 32; off; off >>= 1) s += __shfl_down(s, off, 64);
        if (lane == 0) red[wq] = s;
    }
    __syncthreads();
    if (tid == 0) part[blk] = red[0] + red[1];
}

// ---------------------------------------------------------------------------
__global__ __launch_bounds__(512) void k_final(
    const float* __restrict__ part, const float* __restrict__ dec_b,
    float* __restrict__ out)
{
    int tid = threadIdx.x;
    int b = tid >> 6, lane = tid & 63;
    float s = part[b * 128 + lane] + part[b * 128 + 64 + lane];
#pragma unroll
    for (int off = 32; off; off >>= 1) s += __shfl_down(s, off, 64);
    if (lane == 0) out[b] = fmaf(s, 1.0f / (float)L_, dec_b[0]);
}

// ---------------------------------------------------------------------------
extern "C" void kernel_launch(void* const* d_in, const int* in_sizes, int n_in,
                              void* d_out, int out_size, void* d_ws, size_t ws_size,
                              hipStream_t stream)
{
    const float* x         = (const float*)d_in[0];
    const float* enc_w     = (const float*)d_in[1];
    const float* enc_b     = (const float*)d_in[2];
    const float* log_dt    = (const float*)d_in[3];
    const float* log_A_real= (const float*)d_in[4];
    const float* A_imag    = (const float*)d_in[5];
    const float* C_re      = (const float*)d_in[6];
    const float* C_im      = (const float*)d_in[7];
    const float* Dp        = (const float*)d_in[8];
    const float* out_w     = (const float*)d_in[9];
    const float* out_b     = (const float*)d_in[10];
    const float* dec_w     = (const float*)d_in[11];
    const float* dec_b     = (const float*)d_in[12];
    float* out = (float*)d_out;

    char* ws = (char*)d_ws;
    unsigned short* Wh = (unsigned short*)(ws);
    unsigned short* Kh = (unsigned short*)(ws + 65536);
    unsigned short* Ph = (unsigned short*)(ws + 1114112);
    unsigned short* Vh = (unsigned short*)(ws + 2162688);
    float* gy   = (float*)(ws + 3211264);
    float* part = (float*)(ws + 36765696);

    k_prep<<<H_, 256, 0, stream>>>(log_dt, log_A_real, A_imag, C_re, C_im,
                                   out_w, Wh, Kh, Ph, Vh);
    k_s4d<<<B_ * H_, 256, 0, stream>>>(x, enc_w, enc_b, log_dt, log_A_real,
                                       A_imag, Dp, Kh, Ph, Vh, gy);
    k_mix<<<B_ * 128, 256, 0, stream>>>(Wh, gy, out_b, dec_w, part);
    k_final<<<1, 512, 0, stream>>>(part, dec_b, out);
}

// Round 11
// 154.298 us; speedup vs baseline: 1.2633x; 1.1578x over previous
//
#include <hip/hip_runtime.h>
#include <math.h>

// Problem dims (fixed by the reference)
#define B_ 8
#define L_ 8192
#define H_ 128
#define N_ 32
#define C_ 128   // chunks along L
#define T_ 64    // chunk length

// ws layout:
//   Wh   ushort[256*128]     @ 0        (64 KB)  fp16 out_w [g][h]
//   Kh   ushort[128*64*64]   @ 65536    (1 MB)   fp16 Klo[h][t][j] (Toeplitz)
//   Ph   ushort[128*64*64]   @ 1114112  (1 MB)   fp16 P[h][t][m']  (state inj)
//   Vh   ushort[128*64*64]   @ 2162688  (1 MB)   fp16 V[h][m'][j]  (Vandermonde)
//   gy   float[B_*H_*L_]     @ 3211264  (32 MB)  fp32 gy [b][h][l'], l'=t*128+c
//   part float[1024]         @ 36765696 (4 KB)

typedef _Float16 half8 __attribute__((ext_vector_type(8)));
typedef __attribute__((ext_vector_type(4))) float f32x4;

__device__ __forceinline__ float gelu_tanh(float y) {
    float t = 0.7978845608028654f * fmaf(0.044715f, y * y * y, y);
    float e = __expf(2.f * t);
    float th = 1.f - __fdividef(2.f, e + 1.f);
    return 0.5f * y * (1.f + th);
}
__device__ __forceinline__ unsigned short f2h(float f) {
    _Float16 h = (_Float16)f;
    return *(unsigned short*)&h;
}
__device__ __forceinline__ float h2f(unsigned short u) {
    return (float)(*(const _Float16*)&u);
}

// ---------------------------------------------------------------------------
// k_prep: per-h fp16 matrices Klo/P/V + Wh (out_w fp16). Block = h.
// (unchanged from R10)
// ---------------------------------------------------------------------------
__global__ __launch_bounds__(256) void k_prep(
    const float* __restrict__ log_dt, const float* __restrict__ log_A_real,
    const float* __restrict__ A_imag, const float* __restrict__ C_re,
    const float* __restrict__ C_im, const float* __restrict__ out_w,
    unsigned short* __restrict__ Wh, unsigned short* __restrict__ Kh,
    unsigned short* __restrict__ Ph, unsigned short* __restrict__ Vh)
{
    const int h = blockIdx.x;
    const int tid = threadIdx.x;
    __shared__ float2 wtab[65][N_];
    __shared__ float2 coefs[N_];
    __shared__ float Kd[64];

    float dt = expf(log_dt[h]);
#pragma unroll
    for (int it = 0; it < 9; ++it) {
        int idx = it * 256 + tid;
        if (idx < 65 * N_) {
            int d = idx >> 5, n = idx & 31;
            float Ar = -expf(log_A_real[h * N_ + n]);
            float Ai = A_imag[h * N_ + n];
            float ar = dt * Ar * (float)d, ai = dt * Ai * (float)d;
            float er = expf(ar);
            wtab[d][n] = make_float2(er * cosf(ai), er * sinf(ai));
        }
    }
    if (tid < N_) {
        int n = tid;
        float Ar = -expf(log_A_real[h * N_ + n]);
        float Ai = A_imag[h * N_ + n];
        float ar = dt * Ar, ai = dt * Ai;
        float er = expf(ar);
        float wr = er * cosf(ai), wi = er * sinf(ai);
        float inv = 1.f / (Ar * Ar + Ai * Ai);
        float numr = wr - 1.f, numi = wi;
        float qr = (numr * Ar + numi * Ai) * inv;
        float qi = (numi * Ar - numr * Ai) * inv;
        coefs[n] = make_float2(C_re[h * N_ + n] * qr - C_im[h * N_ + n] * qi,
                               C_re[h * N_ + n] * qi + C_im[h * N_ + n] * qr);
    }
    __syncthreads();
    if (tid < 64) {
        float s = 0.f;
#pragma unroll
        for (int n = 0; n < N_; ++n) {
            float2 cf = coefs[n]; float2 w = wtab[tid][n];
            s += cf.x * w.x - cf.y * w.y;
        }
        Kd[tid] = 2.f * s;
    }
    __syncthreads();
#pragma unroll
    for (int it = 0; it < 16; ++it) {
        int idx = it * 256 + tid;              // t*64 + j
        int t = idx >> 6, j = idx & 63;
        Kh[h * 4096 + idx] = f2h((t >= j) ? Kd[t - j] : 0.f);
    }
#pragma unroll
    for (int it = 0; it < 16; ++it) {
        int idx = it * 256 + tid;              // t*64 + m
        int t = idx >> 6, m = idx & 63, n = m & 31;
        float2 cf = coefs[n]; float2 w = wtab[t + 1][n];
        float re = cf.x * w.x - cf.y * w.y;
        float im = cf.x * w.y + cf.y * w.x;
        Ph[h * 4096 + idx] = f2h((m < 32) ? 2.f * re : -2.f * im);
    }
#pragma unroll
    for (int it = 0; it < 16; ++it) {
        int idx = it * 256 + tid;              // m*64 + j
        int m = idx >> 6, j = idx & 63, n = m & 31;
        float2 w = wtab[63 - j][n];
        Vh[h * 4096 + idx] = f2h((m < 32) ? w.x : w.y);
    }
    {   // out_w rows g = 2h, 2h+1 -> fp16
        int g = 2 * h + (tid >> 7), j = tid & 127;
        Wh[g * 128 + j] = f2h(out_w[g * 128 + j]);
    }
}

// ---------------------------------------------------------------------------
// k_s4d: MFMA-Toeplitz S4D, occupancy-tuned. Block=(b,h), 256 threads.
// LDS 38.7KB (was 70.1KB -> 2 blk/CU, 80% stall): E stored fp16 in a scratch
// region overlapped (barrier-protected) with Sx and St. Epilogue reads u from
// Ut (LDS) instead of 32 scattered global x loads per thread.
// ---------------------------------------------------------------------------
__global__ __launch_bounds__(256) void k_s4d(
    const float* __restrict__ x, const float* __restrict__ enc_w,
    const float* __restrict__ enc_b, const float* __restrict__ log_dt,
    const float* __restrict__ log_A_real, const float* __restrict__ A_imag,
    const float* __restrict__ Dp, const unsigned short* __restrict__ Kh,
    const unsigned short* __restrict__ Ph, const unsigned short* __restrict__ Vh,
    float* __restrict__ gy)
{
    const int bh = blockIdx.x;
    const int b = bh >> 7, h = bh & (H_ - 1);
    const int tid = threadIdx.x;
    const int lane = tid & 63, wq = tid >> 6;
    const int mrow = lane & 15, quad = lane >> 4;

    __shared__ unsigned short Ut[C_][72];          // [c][j] fp16 u (18.4 KB)
    __shared__ __align__(16) char scratch[18432];  // E16 / Sx / St (18.4 KB)
    __shared__ float2 wTpow[7][N_];                // 1.8 KB
    unsigned short* E16 = (unsigned short*)scratch;   // [m(64)][c] stride 136
    float2*         Sx  = (float2*)scratch;           // [n(32)][c(64)]
    unsigned short* St  = (unsigned short*)scratch;   // [c(128)][m'] stride 72

    if (tid < N_) {
        int idx = h * N_ + tid;
        float dt = expf(log_dt[h]);
        float Ar = -expf(log_A_real[idx]);
        float Ai = A_imag[idx];
        float ar = dt * Ar * (float)T_, ai = dt * Ai * (float)T_;
        float er = expf(ar);
        float pr = er * cosf(ai), pi = er * sinf(ai);
#pragma unroll
        for (int k = 0; k < 7; ++k) {
            wTpow[k][tid] = make_float2(pr, pi);
            float nr = pr * pr - pi * pi;
            pi = 2.f * pr * pi; pr = nr;
        }
    }

    // ---- stage: u = enc(x) -> Ut[c][j] fp16 (16 float4 = 32 timesteps) ----
    const float ew0 = enc_w[h], ew1 = enc_w[H_ + h], eb = enc_b[h];
    {
        int c = tid >> 1, j0 = (tid & 1) * 32;
        const float4* xp = (const float4*)((const float2*)x + (size_t)b * L_
                                           + c * 64 + j0);
#pragma unroll
        for (int i = 0; i < 16; ++i) {
            float4 xv = xp[i];
            float u0 = fmaf(xv.x, ew0, fmaf(xv.y, ew1, eb));
            float u1 = fmaf(xv.z, ew0, fmaf(xv.w, ew1, eb));
            unsigned int pk = (unsigned)f2h(u0) | ((unsigned)f2h(u1) << 16);
            *(unsigned int*)&Ut[c][j0 + 2 * i] = pk;
        }
    }
    __syncthreads();

    // ---- GEMM E[m 64][c 128] = V[m][j] @ U[j][c] -> fp16 E16 ----
    {
        f32x4 acc[8];
#pragma unroll
        for (int nt = 0; nt < 8; ++nt) acc[nt] = (f32x4){0.f, 0.f, 0.f, 0.f};
        const unsigned short* Arow = Vh + h * 4096 + (wq * 16 + mrow) * 64;
#pragma unroll
        for (int ks = 0; ks < 2; ++ks) {
            int k0 = ks * 32 + quad * 8;
            half8 af = *(const half8*)(Arow + k0);
#pragma unroll
            for (int nt = 0; nt < 8; ++nt) {
                half8 bf = *(const half8*)&Ut[nt * 16 + mrow][k0];
                acc[nt] = __builtin_amdgcn_mfma_f32_16x16x32_f16(
                    af, bf, acc[nt], 0, 0, 0);
            }
        }
#pragma unroll
        for (int nt = 0; nt < 8; ++nt) {
            int cc = nt * 16 + mrow;
#pragma unroll
            for (int r = 0; r < 4; ++r)
                E16[(wq * 16 + quad * 4 + r) * 136 + cc] = f2h(acc[nt][r]);
        }
    }
    __syncthreads();

    // ---- scan over chunks (threads 0..127) ----
    float zr[N_], zi[N_];
    const int sl = tid & 63, wv = (tid >> 6) & 1;
    if (tid < 128) {
        int c = tid;
#pragma unroll
        for (int n = 0; n < N_; ++n) {
            zr[n] = h2f(E16[n * 136 + c]);
            zi[n] = h2f(E16[(32 + n) * 136 + c]);
        }
    }
    __syncthreads();            // all E16 reads done before Sx overwrites
    if (tid < 128) {
#pragma unroll
        for (int k = 0; k < 6; ++k) {
            int s = 1 << k;
            float mask = (sl >= s) ? 1.f : 0.f;
#pragma unroll
            for (int n = 0; n < N_; ++n) {
                float2 q = wTpow[k][n];
                float vr = __shfl_up(zr[n], s, 64);
                float vi = __shfl_up(zi[n], s, 64);
                float adr = fmaf(q.x, vr, -(q.y * vi));
                float adi = fmaf(q.x, vi, q.y * vr);
                zr[n] = fmaf(mask, adr, zr[n]);
                zi[n] = fmaf(mask, adi, zi[n]);
            }
        }
        if (wv == 0) {
#pragma unroll
            for (int n = 0; n < N_; ++n) Sx[n * 64 + sl] = make_float2(zr[n], zi[n]);
        }
    }
    __syncthreads();
    if (tid < 128) {
        if (wv == 1) {
#pragma unroll
            for (int n = 0; n < N_; ++n) {
                float2 q = wTpow[6][n];
                float2 v = Sx[n * 64 + sl];
                zr[n] = fmaf(q.x, v.x, fmaf(-q.y, v.y, zr[n]));
                zi[n] = fmaf(q.x, v.y, fmaf(q.y, v.x, zi[n]));
            }
        }
        bool l0 = (sl == 0);
#pragma unroll
        for (int n = 0; n < N_; ++n) {
            float2 bv = Sx[n * 64 + 63];
            float br = (wv == 1) ? bv.x : 0.f;
            float bi = (wv == 1) ? bv.y : 0.f;
            float tr = __shfl_up(zr[n], 1, 64);
            float ti = __shfl_up(zi[n], 1, 64);
            zr[n] = l0 ? br : tr;
            zi[n] = l0 ? bi : ti;
        }
    }
    __syncthreads();            // all Sx reads done before St overwrites
    if (tid < 128) {
        int c = tid;
#pragma unroll
        for (int n2 = 0; n2 < 16; ++n2) {
            unsigned int p0 = (unsigned)f2h(zr[2 * n2]) |
                              ((unsigned)f2h(zr[2 * n2 + 1]) << 16);
            unsigned int p1 = (unsigned)f2h(zi[2 * n2]) |
                              ((unsigned)f2h(zi[2 * n2 + 1]) << 16);
            *(unsigned int*)&St[c * 72 + 2 * n2] = p0;
            *(unsigned int*)&St[c * 72 + 32 + 2 * n2] = p1;
        }
    }
    __syncthreads();

    // ---- GEMM Y[t][c] = Klo@U + P@S; epilogue u from Ut (LDS) ----
    {
        f32x4 acc[8];
#pragma unroll
        for (int nt = 0; nt < 8; ++nt) acc[nt] = (f32x4){0.f, 0.f, 0.f, 0.f};
        const unsigned short* Krow = Kh + h * 4096 + (wq * 16 + mrow) * 64;
#pragma unroll
        for (int ks = 0; ks < 2; ++ks) {
            int k0 = ks * 32 + quad * 8;
            half8 af = *(const half8*)(Krow + k0);
#pragma unroll
            for (int nt = 0; nt < 8; ++nt) {
                half8 bf = *(const half8*)&Ut[nt * 16 + mrow][k0];
                acc[nt] = __builtin_amdgcn_mfma_f32_16x16x32_f16(
                    af, bf, acc[nt], 0, 0, 0);
            }
        }
        const unsigned short* Prow = Ph + h * 4096 + (wq * 16 + mrow) * 64;
#pragma unroll
        for (int ks = 0; ks < 2; ++ks) {
            int k0 = ks * 32 + quad * 8;
            half8 af = *(const half8*)(Prow + k0);
#pragma unroll
            for (int nt = 0; nt < 8; ++nt) {
                half8 bf = *(const half8*)&St[(nt * 16 + mrow) * 72 + k0];
                acc[nt] = __builtin_amdgcn_mfma_f32_16x16x32_f16(
                    af, bf, acc[nt], 0, 0, 0);
            }
        }
        const float Dh = Dp[h];
        float* gyb = gy + (size_t)bh * L_;
#pragma unroll
        for (int nt = 0; nt < 8; ++nt) {
            int c = nt * 16 + mrow;
#pragma unroll
            for (int r = 0; r < 4; ++r) {
                int t = wq * 16 + quad * 4 + r;
                float u = h2f(Ut[c][t]);
                float y = fmaf(Dh, u, acc[nt][r]);
                gyb[t * 128 + c] = gelu_tanh(y);
            }
        }
    }
}

// ---------------------------------------------------------------------------
// k_mix: fp16 MFMA GLU mix + pooled decode (UNCHANGED — isolate).
// ---------------------------------------------------------------------------
#define BPAD 136
__global__ __launch_bounds__(256) void k_mix(
    const unsigned short* __restrict__ Wh, const float* __restrict__ gy,
    const float* __restrict__ out_b, const float* __restrict__ dec_w,
    float* __restrict__ part)
{
    __shared__ unsigned short Bt[64 * BPAD];
    __shared__ float gx[2 * 4096];
    __shared__ float red[2];

    const int blk = blockIdx.x;                // = b*128 + t*2 + ch
    const int b = blk >> 7;
    const int t = (blk >> 1) & 63, ch = blk & 1;
    const int tid = threadIdx.x;
    const int wq = tid >> 6, lane = tid & 63;

    const float* gsrc = gy + (size_t)(b * H_) * L_ + t * 128 + ch * 64;
#pragma unroll
    for (int it = 0; it < 8; ++it) {
        int idx = it * 256 + tid;
        int h = idx >> 4, v0 = (idx & 15) * 4;
        float4 f = *(const float4*)(gsrc + (size_t)h * L_ + v0);
        Bt[(v0 + 0) * BPAD + h] = f2h(f.x);
        Bt[(v0 + 1) * BPAD + h] = f2h(f.y);
        Bt[(v0 + 2) * BPAD + h] = f2h(f.z);
        Bt[(v0 + 3) * BPAD + h] = f2h(f.w);
    }
    __syncthreads();

    const int gbase = wq * 64;
    const int mrow = lane & 15;
    const int quad = lane >> 4;
    f32x4 acc[4][4];
#pragma unroll
    for (int mt = 0; mt < 4; ++mt)
#pragma unroll
        for (int nt = 0; nt < 4; ++nt)
            acc[mt][nt] = (f32x4){0.f, 0.f, 0.f, 0.f};

#pragma unroll
    for (int k = 0; k < 4; ++k) {
        const int h0 = k * 32 + quad * 8;
        half8 bfr[4];
#pragma unroll
        for (int nt = 0; nt < 4; ++nt) {
            int v = nt * 16 + mrow;
            bfr[nt] = *(const half8*)(Bt + v * BPAD + h0);
        }
#pragma unroll
        for (int mt = 0; mt < 4; ++mt) {
            int g = gbase + mt * 16 + mrow;
            half8 ah = *(const half8*)(Wh + g * 128 + h0);
#pragma unroll
            for (int nt = 0; nt < 4; ++nt) {
                acc[mt][nt] = __builtin_amdgcn_mfma_f32_16x16x32_f16(
                    ah, bfr[nt], acc[mt][nt], 0, 0, 0);
            }
        }
    }

    float4 ob[4];
#pragma unroll
    for (int mt = 0; mt < 4; ++mt)
        ob[mt] = *(const float4*)(out_b + gbase + mt * 16 + quad * 4);

    if (wq >= 2) {
        float* gxw = gx + (wq - 2) * 4096;
#pragma unroll
        for (int mt = 0; mt < 4; ++mt)
#pragma unroll
            for (int nt = 0; nt < 4; ++nt)
#pragma unroll
                for (int r = 0; r < 4; ++r) {
                    float zg = acc[mt][nt][r] + ob[mt][r];
                    gxw[((mt * 4 + nt) * 4 + r) * 64 + lane] =
                        __fdividef(1.f, 1.f + __expf(-zg));
                }
    }
    __syncthreads();

    if (wq < 2) {
        const float* gxw = gx + wq * 4096;
        float4 dv[4];
#pragma unroll
        for (int mt = 0; mt < 4; ++mt)
            dv[mt] = *(const float4*)(dec_w + gbase + mt * 16 + quad * 4);
        float s = 0.f;
#pragma unroll
        for (int mt = 0; mt < 4; ++mt)
#pragma unroll
            for (int nt = 0; nt < 4; ++nt)
#pragma unroll
                for (int r = 0; r < 4; ++r) {
                    float a = acc[mt][nt][r] + ob[mt][r];
                    float sg = gxw[((mt * 4 + nt) * 4 + r) * 64 + lane];
                    s = fmaf(dv[mt][r], a * sg, s);
                }
#pragma unroll
        for (int off = 32; off; off >>= 1) s += __shfl_down(s, off, 64);
        if (lane == 0) red[wq] = s;
    }
    __syncthreads();
    if (tid == 0) part[blk] = red[0] + red[1];
}

// ---------------------------------------------------------------------------
__global__ __launch_bounds__(512) void k_final(
    const float* __restrict__ part, const float* __restrict__ dec_b,
    float* __restrict__ out)
{
    int tid = threadIdx.x;
    int b = tid >> 6, lane = tid & 63;
    float s = part[b * 128 + lane] + part[b * 128 + 64 + lane];
#pragma unroll
    for (int off = 32; off; off >>= 1) s += __shfl_down(s, off, 64);
    if (lane == 0) out[b] = fmaf(s, 1.0f / (float)L_, dec_b[0]);
}

// ---------------------------------------------------------------------------
extern "C" void kernel_launch(void* const* d_in, const int* in_sizes, int n_in,
                              void* d_out, int out_size, void* d_ws, size_t ws_size,
                              hipStream_t stream)
{
    const float* x         = (const float*)d_in[0];
    const float* enc_w     = (const float*)d_in[1];
    const float* enc_b     = (const float*)d_in[2];
    const float* log_dt    = (const float*)d_in[3];
    const float* log_A_real= (const float*)d_in[4];
    const float* A_imag    = (const float*)d_in[5];
    const float* C_re      = (const float*)d_in[6];
    const float* C_im      = (const float*)d_in[7];
    const float* Dp        = (const float*)d_in[8];
    const float* out_w     = (const float*)d_in[9];
    const float* out_b     = (const float*)d_in[10];
    const float* dec_w     = (const float*)d_in[11];
    const float* dec_b     = (const float*)d_in[12];
    float* out = (float*)d_out;

    char* ws = (char*)d_ws;
    unsigned short* Wh = (unsigned short*)(ws);
    unsigned short* Kh = (unsigned short*)(ws + 65536);
    unsigned short* Ph = (unsigned short*)(ws + 1114112);
    unsigned short* Vh = (unsigned short*)(ws + 2162688);
    float* gy   = (float*)(ws + 3211264);
    float* part = (float*)(ws + 36765696);

    k_prep<<<H_, 256, 0, stream>>>(log_dt, log_A_real, A_imag, C_re, C_im,
                                   out_w, Wh, Kh, Ph, Vh);
    k_s4d<<<B_ * H_, 256, 0, stream>>>(x, enc_w, enc_b, log_dt, log_A_real,
                                       A_imag, Dp, Kh, Ph, Vh, gy);
    k_mix<<<B_ * 128, 256, 0, stream>>>(Wh, gy, out_b, dec_w, part);
    k_final<<<1, 512, 0, stream>>>(part, dec_b, out);
}

// Round 12
// 152.559 us; speedup vs baseline: 1.2777x; 1.0114x over previous
//
#include <hip/hip_runtime.h>
#include <math.h>

// Problem dims (fixed by the reference)
#define B_ 8
#define L_ 8192
#define H_ 128
#define N_ 32
#define C_ 128   // chunks along L
#define T_ 64    // chunk length

// ws layout:
//   Wh   ushort[256*128]     @ 0        (64 KB)  fp16 out_w [g][h]
//   Kh   ushort[128*64*64]   @ 65536    (1 MB)   fp16 Klo[h][t][j] (Toeplitz)
//   Ph   ushort[128*64*64]   @ 1114112  (1 MB)   fp16 P[h][t][m']  (state inj)
//   Vh   ushort[128*64*64]   @ 2162688  (1 MB)   fp16 V[h][m'][j]  (Vandermonde)
//   gy   float[B_*H_*L_]     @ 3211264  (32 MB)  fp32 gy [b][h][l'], l'=t*128+c
//   part float[1024]         @ 36765696 (4 KB)

typedef _Float16 half8 __attribute__((ext_vector_type(8)));
typedef __attribute__((ext_vector_type(4))) float f32x4;

__device__ __forceinline__ float gelu_tanh(float y) {
    float t = 0.7978845608028654f * fmaf(0.044715f, y * y * y, y);
    float e = __expf(2.f * t);
    float th = 1.f - __fdividef(2.f, e + 1.f);
    return 0.5f * y * (1.f + th);
}
__device__ __forceinline__ unsigned short f2h(float f) {
    _Float16 h = (_Float16)f;
    return *(unsigned short*)&h;
}
__device__ __forceinline__ float h2f(unsigned short u) {
    return (float)(*(const _Float16*)&u);
}

// ---------------------------------------------------------------------------
// k_prep: per-h fp16 matrices Klo/P/V + Wh (out_w fp16). Block = h.
// (unchanged from R10/R11)
// ---------------------------------------------------------------------------
__global__ __launch_bounds__(256) void k_prep(
    const float* __restrict__ log_dt, const float* __restrict__ log_A_real,
    const float* __restrict__ A_imag, const float* __restrict__ C_re,
    const float* __restrict__ C_im, const float* __restrict__ out_w,
    unsigned short* __restrict__ Wh, unsigned short* __restrict__ Kh,
    unsigned short* __restrict__ Ph, unsigned short* __restrict__ Vh)
{
    const int h = blockIdx.x;
    const int tid = threadIdx.x;
    __shared__ float2 wtab[65][N_];
    __shared__ float2 coefs[N_];
    __shared__ float Kd[64];

    float dt = expf(log_dt[h]);
#pragma unroll
    for (int it = 0; it < 9; ++it) {
        int idx = it * 256 + tid;
        if (idx < 65 * N_) {
            int d = idx >> 5, n = idx & 31;
            float Ar = -expf(log_A_real[h * N_ + n]);
            float Ai = A_imag[h * N_ + n];
            float ar = dt * Ar * (float)d, ai = dt * Ai * (float)d;
            float er = expf(ar);
            wtab[d][n] = make_float2(er * cosf(ai), er * sinf(ai));
        }
    }
    if (tid < N_) {
        int n = tid;
        float Ar = -expf(log_A_real[h * N_ + n]);
        float Ai = A_imag[h * N_ + n];
        float ar = dt * Ar, ai = dt * Ai;
        float er = expf(ar);
        float wr = er * cosf(ai), wi = er * sinf(ai);
        float inv = 1.f / (Ar * Ar + Ai * Ai);
        float numr = wr - 1.f, numi = wi;
        float qr = (numr * Ar + numi * Ai) * inv;
        float qi = (numi * Ar - numr * Ai) * inv;
        coefs[n] = make_float2(C_re[h * N_ + n] * qr - C_im[h * N_ + n] * qi,
                               C_re[h * N_ + n] * qi + C_im[h * N_ + n] * qr);
    }
    __syncthreads();
    if (tid < 64) {
        float s = 0.f;
#pragma unroll
        for (int n = 0; n < N_; ++n) {
            float2 cf = coefs[n]; float2 w = wtab[tid][n];
            s += cf.x * w.x - cf.y * w.y;
        }
        Kd[tid] = 2.f * s;
    }
    __syncthreads();
#pragma unroll
    for (int it = 0; it < 16; ++it) {
        int idx = it * 256 + tid;              // t*64 + j
        int t = idx >> 6, j = idx & 63;
        Kh[h * 4096 + idx] = f2h((t >= j) ? Kd[t - j] : 0.f);
    }
#pragma unroll
    for (int it = 0; it < 16; ++it) {
        int idx = it * 256 + tid;              // t*64 + m
        int t = idx >> 6, m = idx & 63, n = m & 31;
        float2 cf = coefs[n]; float2 w = wtab[t + 1][n];
        float re = cf.x * w.x - cf.y * w.y;
        float im = cf.x * w.y + cf.y * w.x;
        Ph[h * 4096 + idx] = f2h((m < 32) ? 2.f * re : -2.f * im);
    }
#pragma unroll
    for (int it = 0; it < 16; ++it) {
        int idx = it * 256 + tid;              // m*64 + j
        int m = idx >> 6, j = idx & 63, n = m & 31;
        float2 w = wtab[63 - j][n];
        Vh[h * 4096 + idx] = f2h((m < 32) ? w.x : w.y);
    }
    {   // out_w rows g = 2h, 2h+1 -> fp16
        int g = 2 * h + (tid >> 7), j = tid & 127;
        Wh[g * 128 + j] = f2h(out_w[g * 128 + j]);
    }
}

// ---------------------------------------------------------------------------
// k_s4d: MFMA-Toeplitz S4D (UNCHANGED from R11 — proven <47us).
// ---------------------------------------------------------------------------
__global__ __launch_bounds__(256) void k_s4d(
    const float* __restrict__ x, const float* __restrict__ enc_w,
    const float* __restrict__ enc_b, const float* __restrict__ log_dt,
    const float* __restrict__ log_A_real, const float* __restrict__ A_imag,
    const float* __restrict__ Dp, const unsigned short* __restrict__ Kh,
    const unsigned short* __restrict__ Ph, const unsigned short* __restrict__ Vh,
    float* __restrict__ gy)
{
    const int bh = blockIdx.x;
    const int b = bh >> 7, h = bh & (H_ - 1);
    const int tid = threadIdx.x;
    const int lane = tid & 63, wq = tid >> 6;
    const int mrow = lane & 15, quad = lane >> 4;

    __shared__ unsigned short Ut[C_][72];          // [c][j] fp16 u (18.4 KB)
    __shared__ __align__(16) char scratch[18432];  // E16 / Sx / St (18.4 KB)
    __shared__ float2 wTpow[7][N_];                // 1.8 KB
    unsigned short* E16 = (unsigned short*)scratch;   // [m(64)][c] stride 136
    float2*         Sx  = (float2*)scratch;           // [n(32)][c(64)]
    unsigned short* St  = (unsigned short*)scratch;   // [c(128)][m'] stride 72

    if (tid < N_) {
        int idx = h * N_ + tid;
        float dt = expf(log_dt[h]);
        float Ar = -expf(log_A_real[idx]);
        float Ai = A_imag[idx];
        float ar = dt * Ar * (float)T_, ai = dt * Ai * (float)T_;
        float er = expf(ar);
        float pr = er * cosf(ai), pi = er * sinf(ai);
#pragma unroll
        for (int k = 0; k < 7; ++k) {
            wTpow[k][tid] = make_float2(pr, pi);
            float nr = pr * pr - pi * pi;
            pi = 2.f * pr * pi; pr = nr;
        }
    }

    // ---- stage: u = enc(x) -> Ut[c][j] fp16 ----
    const float ew0 = enc_w[h], ew1 = enc_w[H_ + h], eb = enc_b[h];
    {
        int c = tid >> 1, j0 = (tid & 1) * 32;
        const float4* xp = (const float4*)((const float2*)x + (size_t)b * L_
                                           + c * 64 + j0);
#pragma unroll
        for (int i = 0; i < 16; ++i) {
            float4 xv = xp[i];
            float u0 = fmaf(xv.x, ew0, fmaf(xv.y, ew1, eb));
            float u1 = fmaf(xv.z, ew0, fmaf(xv.w, ew1, eb));
            unsigned int pk = (unsigned)f2h(u0) | ((unsigned)f2h(u1) << 16);
            *(unsigned int*)&Ut[c][j0 + 2 * i] = pk;
        }
    }
    __syncthreads();

    // ---- GEMM E[m 64][c 128] = V[m][j] @ U[j][c] -> fp16 E16 ----
    {
        f32x4 acc[8];
#pragma unroll
        for (int nt = 0; nt < 8; ++nt) acc[nt] = (f32x4){0.f, 0.f, 0.f, 0.f};
        const unsigned short* Arow = Vh + h * 4096 + (wq * 16 + mrow) * 64;
#pragma unroll
        for (int ks = 0; ks < 2; ++ks) {
            int k0 = ks * 32 + quad * 8;
            half8 af = *(const half8*)(Arow + k0);
#pragma unroll
            for (int nt = 0; nt < 8; ++nt) {
                half8 bf = *(const half8*)&Ut[nt * 16 + mrow][k0];
                acc[nt] = __builtin_amdgcn_mfma_f32_16x16x32_f16(
                    af, bf, acc[nt], 0, 0, 0);
            }
        }
#pragma unroll
        for (int nt = 0; nt < 8; ++nt) {
            int cc = nt * 16 + mrow;
#pragma unroll
            for (int r = 0; r < 4; ++r)
                E16[(wq * 16 + quad * 4 + r) * 136 + cc] = f2h(acc[nt][r]);
        }
    }
    __syncthreads();

    // ---- scan over chunks (threads 0..127) ----
    float zr[N_], zi[N_];
    const int sl = tid & 63, wv = (tid >> 6) & 1;
    if (tid < 128) {
        int c = tid;
#pragma unroll
        for (int n = 0; n < N_; ++n) {
            zr[n] = h2f(E16[n * 136 + c]);
            zi[n] = h2f(E16[(32 + n) * 136 + c]);
        }
    }
    __syncthreads();            // all E16 reads done before Sx overwrites
    if (tid < 128) {
#pragma unroll
        for (int k = 0; k < 6; ++k) {
            int s = 1 << k;
            float mask = (sl >= s) ? 1.f : 0.f;
#pragma unroll
            for (int n = 0; n < N_; ++n) {
                float2 q = wTpow[k][n];
                float vr = __shfl_up(zr[n], s, 64);
                float vi = __shfl_up(zi[n], s, 64);
                float adr = fmaf(q.x, vr, -(q.y * vi));
                float adi = fmaf(q.x, vi, q.y * vr);
                zr[n] = fmaf(mask, adr, zr[n]);
                zi[n] = fmaf(mask, adi, zi[n]);
            }
        }
        if (wv == 0) {
#pragma unroll
            for (int n = 0; n < N_; ++n) Sx[n * 64 + sl] = make_float2(zr[n], zi[n]);
        }
    }
    __syncthreads();
    if (tid < 128) {
        if (wv == 1) {
#pragma unroll
            for (int n = 0; n < N_; ++n) {
                float2 q = wTpow[6][n];
                float2 v = Sx[n * 64 + sl];
                zr[n] = fmaf(q.x, v.x, fmaf(-q.y, v.y, zr[n]));
                zi[n] = fmaf(q.x, v.y, fmaf(q.y, v.x, zi[n]));
            }
        }
        bool l0 = (sl == 0);
#pragma unroll
        for (int n = 0; n < N_; ++n) {
            float2 bv = Sx[n * 64 + 63];
            float br = (wv == 1) ? bv.x : 0.f;
            float bi = (wv == 1) ? bv.y : 0.f;
            float tr = __shfl_up(zr[n], 1, 64);
            float ti = __shfl_up(zi[n], 1, 64);
            zr[n] = l0 ? br : tr;
            zi[n] = l0 ? bi : ti;
        }
    }
    __syncthreads();            // all Sx reads done before St overwrites
    if (tid < 128) {
        int c = tid;
#pragma unroll
        for (int n2 = 0; n2 < 16; ++n2) {
            unsigned int p0 = (unsigned)f2h(zr[2 * n2]) |
                              ((unsigned)f2h(zr[2 * n2 + 1]) << 16);
            unsigned int p1 = (unsigned)f2h(zi[2 * n2]) |
                              ((unsigned)f2h(zi[2 * n2 + 1]) << 16);
            *(unsigned int*)&St[c * 72 + 2 * n2] = p0;
            *(unsigned int*)&St[c * 72 + 32 + 2 * n2] = p1;
        }
    }
    __syncthreads();

    // ---- GEMM Y[t][c] = Klo@U + P@S; epilogue u from Ut (LDS) ----
    {
        f32x4 acc[8];
#pragma unroll
        for (int nt = 0; nt < 8; ++nt) acc[nt] = (f32x4){0.f, 0.f, 0.f, 0.f};
        const unsigned short* Krow = Kh + h * 4096 + (wq * 16 + mrow) * 64;
#pragma unroll
        for (int ks = 0; ks < 2; ++ks) {
            int k0 = ks * 32 + quad * 8;
            half8 af = *(const half8*)(Krow + k0);
#pragma unroll
            for (int nt = 0; nt < 8; ++nt) {
                half8 bf = *(const half8*)&Ut[nt * 16 + mrow][k0];
                acc[nt] = __builtin_amdgcn_mfma_f32_16x16x32_f16(
                    af, bf, acc[nt], 0, 0, 0);
            }
        }
        const unsigned short* Prow = Ph + h * 4096 + (wq * 16 + mrow) * 64;
#pragma unroll
        for (int ks = 0; ks < 2; ++ks) {
            int k0 = ks * 32 + quad * 8;
            half8 af = *(const half8*)(Prow + k0);
#pragma unroll
            for (int nt = 0; nt < 8; ++nt) {
                half8 bf = *(const half8*)&St[(nt * 16 + mrow) * 72 + k0];
                acc[nt] = __builtin_amdgcn_mfma_f32_16x16x32_f16(
                    af, bf, acc[nt], 0, 0, 0);
            }
        }
        const float Dh = Dp[h];
        float* gyb = gy + (size_t)bh * L_;
#pragma unroll
        for (int nt = 0; nt < 8; ++nt) {
            int c = nt * 16 + mrow;
#pragma unroll
            for (int r = 0; r < 4; ++r) {
                int t = wq * 16 + quad * 4 + r;
                float u = h2f(Ut[c][t]);
                float y = fmaf(Dh, u, acc[nt][r]);
                gyb[t * 128 + c] = gelu_tanh(y);
            }
        }
    }
}

// ---------------------------------------------------------------------------
// k_mix: fp16 MFMA GLU mix + pooled decode. RESTRUCTURED: each wave owns the
// matching a-strip [32wq,32wq+32) AND gate strip [128+32wq,...) -> GLU is
// in-register (identical C-fragment lane mapping), no 32KB gate LDS, no
// half-idle epilogue. LDS 50->17.5 KB.
// ---------------------------------------------------------------------------
#define BPAD 136
__global__ __launch_bounds__(256) void k_mix(
    const unsigned short* __restrict__ Wh, const float* __restrict__ gy,
    const float* __restrict__ out_b, const float* __restrict__ dec_w,
    float* __restrict__ part)
{
    __shared__ unsigned short Bt[64 * BPAD];   // [v][h] fp16 tile (17.4 KB)
    __shared__ float red[4];

    const int blk = blockIdx.x;                // = b*128 + t*2 + ch
    const int b = blk >> 7;
    const int t = (blk >> 1) & 63, ch = blk & 1;
    const int tid = threadIdx.x;
    const int wq = tid >> 6, lane = tid & 63;

    // ---- stage: 128h x 64v fp32 -> fp16 transposed ----
    const float* gsrc = gy + (size_t)(b * H_) * L_ + t * 128 + ch * 64;
#pragma unroll
    for (int it = 0; it < 8; ++it) {
        int idx = it * 256 + tid;
        int h = idx >> 4, v0 = (idx & 15) * 4;
        float4 f = *(const float4*)(gsrc + (size_t)h * L_ + v0);
        Bt[(v0 + 0) * BPAD + h] = f2h(f.x);
        Bt[(v0 + 1) * BPAD + h] = f2h(f.y);
        Bt[(v0 + 2) * BPAD + h] = f2h(f.z);
        Bt[(v0 + 3) * BPAD + h] = f2h(f.w);
    }
    __syncthreads();

    const int ga = wq * 32;                    // a-strip base (this wave)
    const int gg = 128 + wq * 32;              // gate-strip base (this wave)
    const int mrow = lane & 15;
    const int quad = lane >> 4;
    f32x4 accA[2][4], accG[2][4];
#pragma unroll
    for (int mt = 0; mt < 2; ++mt)
#pragma unroll
        for (int nt = 0; nt < 4; ++nt) {
            accA[mt][nt] = (f32x4){0.f, 0.f, 0.f, 0.f};
            accG[mt][nt] = (f32x4){0.f, 0.f, 0.f, 0.f};
        }

#pragma unroll
    for (int k = 0; k < 4; ++k) {
        const int h0 = k * 32 + quad * 8;
        half8 bfr[4];
#pragma unroll
        for (int nt = 0; nt < 4; ++nt) {
            int v = nt * 16 + mrow;
            bfr[nt] = *(const half8*)(Bt + v * BPAD + h0);
        }
#pragma unroll
        for (int mt = 0; mt < 2; ++mt) {
            half8 ah = *(const half8*)(Wh + (ga + mt * 16 + mrow) * 128 + h0);
            half8 ag = *(const half8*)(Wh + (gg + mt * 16 + mrow) * 128 + h0);
#pragma unroll
            for (int nt = 0; nt < 4; ++nt) {
                accA[mt][nt] = __builtin_amdgcn_mfma_f32_16x16x32_f16(
                    ah, bfr[nt], accA[mt][nt], 0, 0, 0);
                accG[mt][nt] = __builtin_amdgcn_mfma_f32_16x16x32_f16(
                    ag, bfr[nt], accG[mt][nt], 0, 0, 0);
            }
        }
    }

    // ---- in-register GLU + dec dot + pool ----
    float s = 0.f;
#pragma unroll
    for (int mt = 0; mt < 2; ++mt) {
        float4 obA = *(const float4*)(out_b + ga + mt * 16 + quad * 4);
        float4 obG = *(const float4*)(out_b + gg + mt * 16 + quad * 4);
        float4 dv  = *(const float4*)(dec_w + ga + mt * 16 + quad * 4);
#pragma unroll
        for (int nt = 0; nt < 4; ++nt) {
#pragma unroll
            for (int r = 0; r < 4; ++r) {
                float a  = accA[mt][nt][r] + ((const float*)&obA)[r];
                float zg = accG[mt][nt][r] + ((const float*)&obG)[r];
                float sig = __fdividef(1.f, 1.f + __expf(-zg));
                s = fmaf(((const float*)&dv)[r], a * sig, s);
            }
        }
    }
#pragma unroll
    for (int off = 32; off; off >>= 1) s += __shfl_down(s, off, 64);
    if (lane == 0) red[wq] = s;
    __syncthreads();
    if (tid == 0) part[blk] = red[0] + red[1] + red[2] + red[3];
}

// ---------------------------------------------------------------------------
__global__ __launch_bounds__(512) void k_final(
    const float* __restrict__ part, const float* __restrict__ dec_b,
    float* __restrict__ out)
{
    int tid = threadIdx.x;
    int b = tid >> 6, lane = tid & 63;
    float s = part[b * 128 + lane] + part[b * 128 + 64 + lane];
#pragma unroll
    for (int off = 32; off; off >>= 1) s += __shfl_down(s, off, 64);
    if (lane == 0) out[b] = fmaf(s, 1.0f / (float)L_, dec_b[0]);
}

// ---------------------------------------------------------------------------
extern "C" void kernel_launch(void* const* d_in, const int* in_sizes, int n_in,
                              void* d_out, int out_size, void* d_ws, size_t ws_size,
                              hipStream_t stream)
{
    const float* x         = (const float*)d_in[0];
    const float* enc_w     = (const float*)d_in[1];
    const float* enc_b     = (const float*)d_in[2];
    const float* log_dt    = (const float*)d_in[3];
    const float* log_A_real= (const float*)d_in[4];
    const float* A_imag    = (const float*)d_in[5];
    const float* C_re      = (const float*)d_in[6];
    const float* C_im      = (const float*)d_in[7];
    const float* Dp        = (const float*)d_in[8];
    const float* out_w     = (const float*)d_in[9];
    const float* out_b     = (const float*)d_in[10];
    const float* dec_w     = (const float*)d_in[11];
    const float* dec_b     = (const float*)d_in[12];
    float* out = (float*)d_out;

    char* ws = (char*)d_ws;
    unsigned short* Wh = (unsigned short*)(ws);
    unsigned short* Kh = (unsigned short*)(ws + 65536);
    unsigned short* Ph = (unsigned short*)(ws + 1114112);
    unsigned short* Vh = (unsigned short*)(ws + 2162688);
    float* gy   = (float*)(ws + 3211264);
    float* part = (float*)(ws + 36765696);

    k_prep<<<H_, 256, 0, stream>>>(log_dt, log_A_real, A_imag, C_re, C_im,
                                   out_w, Wh, Kh, Ph, Vh);
    k_s4d<<<B_ * H_, 256, 0, stream>>>(x, enc_w, enc_b, log_dt, log_A_real,
                                       A_imag, Dp, Kh, Ph, Vh, gy);
    k_mix<<<B_ * 128, 256, 0, stream>>>(Wh, gy, out_b, dec_w, part);
    k_final<<<1, 512, 0, stream>>>(part, dec_b, out);
}

// Round 13
// 144.385 us; speedup vs baseline: 1.3500x; 1.0566x over previous
//
#include <hip/hip_runtime.h>
#include <math.h>

// Problem dims (fixed by the reference)
#define B_ 8
#define L_ 8192
#define H_ 128
#define N_ 32
#define C_ 128   // chunks along L
#define T_ 64    // chunk length

// ws layout:
//   Wh   ushort[256*128]     @ 0        (64 KB)  fp16 out_w [g][h]
//   Kh   ushort[128*64*64]   @ 65536    (1 MB)   fp16 Klo[h][t][j] (Toeplitz)
//   Ph   ushort[128*64*64]   @ 1114112  (1 MB)   fp16 P[h][t][m']  (state inj)
//   Vh   ushort[128*64*64]   @ 2162688  (1 MB)   fp16 V[h][m'][j]  (Vandermonde)
//   gy   float[B_*H_*L_]     @ 3211264  (32 MB)  fp32 gy [b][h][l'], l'=t*128+c
//   part float[1024]         @ 36765696 (4 KB)

typedef _Float16 half8 __attribute__((ext_vector_type(8)));
typedef __attribute__((ext_vector_type(4))) float f32x4;

__device__ __forceinline__ float gelu_tanh(float y) {
    float t = 0.7978845608028654f * fmaf(0.044715f, y * y * y, y);
    float e = __expf(2.f * t);
    float th = 1.f - __fdividef(2.f, e + 1.f);
    return 0.5f * y * (1.f + th);
}
__device__ __forceinline__ unsigned short f2h(float f) {
    _Float16 h = (_Float16)f;
    return *(unsigned short*)&h;
}
__device__ __forceinline__ float h2f(unsigned short u) {
    return (float)(*(const _Float16*)&u);
}

// ---------------------------------------------------------------------------
// k_prep: per-h fp16 matrices Klo/P/V + Wh (out_w fp16). Block = h.
// (unchanged)
// ---------------------------------------------------------------------------
__global__ __launch_bounds__(256) void k_prep(
    const float* __restrict__ log_dt, const float* __restrict__ log_A_real,
    const float* __restrict__ A_imag, const float* __restrict__ C_re,
    const float* __restrict__ C_im, const float* __restrict__ out_w,
    unsigned short* __restrict__ Wh, unsigned short* __restrict__ Kh,
    unsigned short* __restrict__ Ph, unsigned short* __restrict__ Vh)
{
    const int h = blockIdx.x;
    const int tid = threadIdx.x;
    __shared__ float2 wtab[65][N_];
    __shared__ float2 coefs[N_];
    __shared__ float Kd[64];

    float dt = expf(log_dt[h]);
#pragma unroll
    for (int it = 0; it < 9; ++it) {
        int idx = it * 256 + tid;
        if (idx < 65 * N_) {
            int d = idx >> 5, n = idx & 31;
            float Ar = -expf(log_A_real[h * N_ + n]);
            float Ai = A_imag[h * N_ + n];
            float ar = dt * Ar * (float)d, ai = dt * Ai * (float)d;
            float er = expf(ar);
            wtab[d][n] = make_float2(er * cosf(ai), er * sinf(ai));
        }
    }
    if (tid < N_) {
        int n = tid;
        float Ar = -expf(log_A_real[h * N_ + n]);
        float Ai = A_imag[h * N_ + n];
        float ar = dt * Ar, ai = dt * Ai;
        float er = expf(ar);
        float wr = er * cosf(ai), wi = er * sinf(ai);
        float inv = 1.f / (Ar * Ar + Ai * Ai);
        float numr = wr - 1.f, numi = wi;
        float qr = (numr * Ar + numi * Ai) * inv;
        float qi = (numi * Ar - numr * Ai) * inv;
        coefs[n] = make_float2(C_re[h * N_ + n] * qr - C_im[h * N_ + n] * qi,
                               C_re[h * N_ + n] * qi + C_im[h * N_ + n] * qr);
    }
    __syncthreads();
    if (tid < 64) {
        float s = 0.f;
#pragma unroll
        for (int n = 0; n < N_; ++n) {
            float2 cf = coefs[n]; float2 w = wtab[tid][n];
            s += cf.x * w.x - cf.y * w.y;
        }
        Kd[tid] = 2.f * s;
    }
    __syncthreads();
#pragma unroll
    for (int it = 0; it < 16; ++it) {
        int idx = it * 256 + tid;              // t*64 + j
        int t = idx >> 6, j = idx & 63;
        Kh[h * 4096 + idx] = f2h((t >= j) ? Kd[t - j] : 0.f);
    }
#pragma unroll
    for (int it = 0; it < 16; ++it) {
        int idx = it * 256 + tid;              // t*64 + m
        int t = idx >> 6, m = idx & 63, n = m & 31;
        float2 cf = coefs[n]; float2 w = wtab[t + 1][n];
        float re = cf.x * w.x - cf.y * w.y;
        float im = cf.x * w.y + cf.y * w.x;
        Ph[h * 4096 + idx] = f2h((m < 32) ? 2.f * re : -2.f * im);
    }
#pragma unroll
    for (int it = 0; it < 16; ++it) {
        int idx = it * 256 + tid;              // m*64 + j
        int m = idx >> 6, j = idx & 63, n = m & 31;
        float2 w = wtab[63 - j][n];
        Vh[h * 4096 + idx] = f2h((m < 32) ? w.x : w.y);
    }
    {   // out_w rows g = 2h, 2h+1 -> fp16
        int g = 2 * h + (tid >> 7), j = tid & 127;
        Wh[g * 128 + j] = f2h(out_w[g * 128 + j]);
    }
}

// ---------------------------------------------------------------------------
// k_s4d: MFMA-Toeplitz S4D. Block=(b,h), 256 threads.
// R13: scan spread over all 4 waves (wave = (c-half, n-half), 16 n / thread,
// 32 state VGPRs) to cut peak VGPR 144 -> target <=128 (4 waves/SIMD) and
// remove the half-idle scan phase. GEMMs / staging / stores unchanged.
// ---------------------------------------------------------------------------
__global__ __launch_bounds__(256) void k_s4d(
    const float* __restrict__ x, const float* __restrict__ enc_w,
    const float* __restrict__ enc_b, const float* __restrict__ log_dt,
    const float* __restrict__ log_A_real, const float* __restrict__ A_imag,
    const float* __restrict__ Dp, const unsigned short* __restrict__ Kh,
    const unsigned short* __restrict__ Ph, const unsigned short* __restrict__ Vh,
    float* __restrict__ gy)
{
    const int bh = blockIdx.x;
    const int b = bh >> 7, h = bh & (H_ - 1);
    const int tid = threadIdx.x;
    const int lane = tid & 63, wq = tid >> 6;
    const int mrow = lane & 15, quad = lane >> 4;

    __shared__ unsigned short Ut[C_][72];          // [c][j] fp16 u (18.4 KB)
    __shared__ __align__(16) char scratch[18432];  // E16 / Sx / St (18.4 KB)
    __shared__ float2 wTpow[7][N_];                // 1.8 KB
    unsigned short* E16 = (unsigned short*)scratch;   // [m(64)][c] stride 136
    float2*         Sx  = (float2*)scratch;           // [n(32)][c(64)]
    unsigned short* St  = (unsigned short*)scratch;   // [c(128)][m'] stride 72

    if (tid < N_) {
        int idx = h * N_ + tid;
        float dt = expf(log_dt[h]);
        float Ar = -expf(log_A_real[idx]);
        float Ai = A_imag[idx];
        float ar = dt * Ar * (float)T_, ai = dt * Ai * (float)T_;
        float er = expf(ar);
        float pr = er * cosf(ai), pi = er * sinf(ai);
#pragma unroll
        for (int k = 0; k < 7; ++k) {
            wTpow[k][tid] = make_float2(pr, pi);
            float nr = pr * pr - pi * pi;
            pi = 2.f * pr * pi; pr = nr;
        }
    }

    // ---- stage: u = enc(x) -> Ut[c][j] fp16 ----
    const float ew0 = enc_w[h], ew1 = enc_w[H_ + h], eb = enc_b[h];
    {
        int c = tid >> 1, j0 = (tid & 1) * 32;
        const float4* xp = (const float4*)((const float2*)x + (size_t)b * L_
                                           + c * 64 + j0);
#pragma unroll
        for (int i = 0; i < 16; ++i) {
            float4 xv = xp[i];
            float u0 = fmaf(xv.x, ew0, fmaf(xv.y, ew1, eb));
            float u1 = fmaf(xv.z, ew0, fmaf(xv.w, ew1, eb));
            unsigned int pk = (unsigned)f2h(u0) | ((unsigned)f2h(u1) << 16);
            *(unsigned int*)&Ut[c][j0 + 2 * i] = pk;
        }
    }
    __syncthreads();

    // ---- GEMM E[m 64][c 128] = V[m][j] @ U[j][c] -> fp16 E16 ----
    {
        f32x4 acc[8];
#pragma unroll
        for (int nt = 0; nt < 8; ++nt) acc[nt] = (f32x4){0.f, 0.f, 0.f, 0.f};
        const unsigned short* Arow = Vh + h * 4096 + (wq * 16 + mrow) * 64;
#pragma unroll
        for (int ks = 0; ks < 2; ++ks) {
            int k0 = ks * 32 + quad * 8;
            half8 af = *(const half8*)(Arow + k0);
#pragma unroll
            for (int nt = 0; nt < 8; ++nt) {
                half8 bf = *(const half8*)&Ut[nt * 16 + mrow][k0];
                acc[nt] = __builtin_amdgcn_mfma_f32_16x16x32_f16(
                    af, bf, acc[nt], 0, 0, 0);
            }
        }
#pragma unroll
        for (int nt = 0; nt < 8; ++nt) {
            int cc = nt * 16 + mrow;
#pragma unroll
            for (int r = 0; r < 4; ++r)
                E16[(wq * 16 + quad * 4 + r) * 136 + cc] = f2h(acc[nt][r]);
        }
    }
    __syncthreads();

    // ---- scan: 4 waves, wave = (cHalf, nHalf), 16 n per thread ----
    float zr[16], zi[16];
    const int cHalf = wq & 1, nHalf = wq >> 1;
    const int n0 = nHalf * 16;
    const int c = cHalf * 64 + lane;
#pragma unroll
    for (int j = 0; j < 16; ++j) {
        zr[j] = h2f(E16[(n0 + j) * 136 + c]);
        zi[j] = h2f(E16[(32 + n0 + j) * 136 + c]);
    }
    __syncthreads();            // all E16 reads done before Sx overwrites
#pragma unroll
    for (int k = 0; k < 6; ++k) {
        int s = 1 << k;
        float mask = (lane >= s) ? 1.f : 0.f;
#pragma unroll
        for (int j = 0; j < 16; ++j) {
            float2 q = wTpow[k][n0 + j];
            float vr = __shfl_up(zr[j], s, 64);
            float vi = __shfl_up(zi[j], s, 64);
            float adr = fmaf(q.x, vr, -(q.y * vi));
            float adi = fmaf(q.x, vi, q.y * vr);
            zr[j] = fmaf(mask, adr, zr[j]);
            zi[j] = fmaf(mask, adi, zi[j]);
        }
    }
    if (cHalf == 0) {           // publish inclusive scans of low c-half
#pragma unroll
        for (int j = 0; j < 16; ++j)
            Sx[(n0 + j) * 64 + lane] = make_float2(zr[j], zi[j]);
    }
    __syncthreads();
    if (cHalf == 1) {           // s=64 combine with uniform weight wT^64
#pragma unroll
        for (int j = 0; j < 16; ++j) {
            float2 q = wTpow[6][n0 + j];
            float2 v = Sx[(n0 + j) * 64 + lane];
            zr[j] = fmaf(q.x, v.x, fmaf(-q.y, v.y, zr[j]));
            zi[j] = fmaf(q.x, v.y, fmaf(q.y, v.x, zi[j]));
        }
    }
    {                           // shift by one chunk: S_in[c] = I[c-1]
        bool l0 = (lane == 0);
#pragma unroll
        for (int j = 0; j < 16; ++j) {
            float2 bv = Sx[(n0 + j) * 64 + 63];
            float br = (cHalf == 1) ? bv.x : 0.f;
            float bi = (cHalf == 1) ? bv.y : 0.f;
            float tr = __shfl_up(zr[j], 1, 64);
            float ti = __shfl_up(zi[j], 1, 64);
            zr[j] = l0 ? br : tr;
            zi[j] = l0 ? bi : ti;
        }
    }
    __syncthreads();            // all Sx reads done before St overwrites
    {
#pragma unroll
        for (int j2 = 0; j2 < 8; ++j2) {
            unsigned int p0 = (unsigned)f2h(zr[2 * j2]) |
                              ((unsigned)f2h(zr[2 * j2 + 1]) << 16);
            unsigned int p1 = (unsigned)f2h(zi[2 * j2]) |
                              ((unsigned)f2h(zi[2 * j2 + 1]) << 16);
            *(unsigned int*)&St[c * 72 + n0 + 2 * j2] = p0;
            *(unsigned int*)&St[c * 72 + 32 + n0 + 2 * j2] = p1;
        }
    }
    __syncthreads();

    // ---- GEMM Y[t][c] = Klo@U + P@S; epilogue u from Ut (LDS) ----
    {
        f32x4 acc[8];
#pragma unroll
        for (int nt = 0; nt < 8; ++nt) acc[nt] = (f32x4){0.f, 0.f, 0.f, 0.f};
        const unsigned short* Krow = Kh + h * 4096 + (wq * 16 + mrow) * 64;
#pragma unroll
        for (int ks = 0; ks < 2; ++ks) {
            int k0 = ks * 32 + quad * 8;
            half8 af = *(const half8*)(Krow + k0);
#pragma unroll
            for (int nt = 0; nt < 8; ++nt) {
                half8 bf = *(const half8*)&Ut[nt * 16 + mrow][k0];
                acc[nt] = __builtin_amdgcn_mfma_f32_16x16x32_f16(
                    af, bf, acc[nt], 0, 0, 0);
            }
        }
        const unsigned short* Prow = Ph + h * 4096 + (wq * 16 + mrow) * 64;
#pragma unroll
        for (int ks = 0; ks < 2; ++ks) {
            int k0 = ks * 32 + quad * 8;
            half8 af = *(const half8*)(Prow + k0);
#pragma unroll
            for (int nt = 0; nt < 8; ++nt) {
                half8 bf = *(const half8*)&St[(nt * 16 + mrow) * 72 + k0];
                acc[nt] = __builtin_amdgcn_mfma_f32_16x16x32_f16(
                    af, bf, acc[nt], 0, 0, 0);
            }
        }
        const float Dh = Dp[h];
        float* gyb = gy + (size_t)bh * L_;
#pragma unroll
        for (int nt = 0; nt < 8; ++nt) {
            int cc = nt * 16 + mrow;
#pragma unroll
            for (int r = 0; r < 4; ++r) {
                int t = wq * 16 + quad * 4 + r;
                float u = h2f(Ut[cc][t]);
                float y = fmaf(Dh, u, acc[nt][r]);
                gyb[t * 128 + cc] = gelu_tanh(y);
            }
        }
    }
}

// ---------------------------------------------------------------------------
// k_mix: fp16 MFMA GLU mix + pooled decode (unchanged from R12).
// ---------------------------------------------------------------------------
#define BPAD 136
__global__ __launch_bounds__(256) void k_mix(
    const unsigned short* __restrict__ Wh, const float* __restrict__ gy,
    const float* __restrict__ out_b, const float* __restrict__ dec_w,
    float* __restrict__ part)
{
    __shared__ unsigned short Bt[64 * BPAD];   // [v][h] fp16 tile (17.4 KB)
    __shared__ float red[4];

    const int blk = blockIdx.x;                // = b*128 + t*2 + ch
    const int b = blk >> 7;
    const int t = (blk >> 1) & 63, ch = blk & 1;
    const int tid = threadIdx.x;
    const int wq = tid >> 6, lane = tid & 63;

    const float* gsrc = gy + (size_t)(b * H_) * L_ + t * 128 + ch * 64;
#pragma unroll
    for (int it = 0; it < 8; ++it) {
        int idx = it * 256 + tid;
        int h = idx >> 4, v0 = (idx & 15) * 4;
        float4 f = *(const float4*)(gsrc + (size_t)h * L_ + v0);
        Bt[(v0 + 0) * BPAD + h] = f2h(f.x);
        Bt[(v0 + 1) * BPAD + h] = f2h(f.y);
        Bt[(v0 + 2) * BPAD + h] = f2h(f.z);
        Bt[(v0 + 3) * BPAD + h] = f2h(f.w);
    }
    __syncthreads();

    const int ga = wq * 32;
    const int gg = 128 + wq * 32;
    const int mrow = lane & 15;
    const int quad = lane >> 4;
    f32x4 accA[2][4], accG[2][4];
#pragma unroll
    for (int mt = 0; mt < 2; ++mt)
#pragma unroll
        for (int nt = 0; nt < 4; ++nt) {
            accA[mt][nt] = (f32x4){0.f, 0.f, 0.f, 0.f};
            accG[mt][nt] = (f32x4){0.f, 0.f, 0.f, 0.f};
        }

#pragma unroll
    for (int k = 0; k < 4; ++k) {
        const int h0 = k * 32 + quad * 8;
        half8 bfr[4];
#pragma unroll
        for (int nt = 0; nt < 4; ++nt) {
            int v = nt * 16 + mrow;
            bfr[nt] = *(const half8*)(Bt + v * BPAD + h0);
        }
#pragma unroll
        for (int mt = 0; mt < 2; ++mt) {
            half8 ah = *(const half8*)(Wh + (ga + mt * 16 + mrow) * 128 + h0);
            half8 ag = *(const half8*)(Wh + (gg + mt * 16 + mrow) * 128 + h0);
#pragma unroll
            for (int nt = 0; nt < 4; ++nt) {
                accA[mt][nt] = __builtin_amdgcn_mfma_f32_16x16x32_f16(
                    ah, bfr[nt], accA[mt][nt], 0, 0, 0);
                accG[mt][nt] = __builtin_amdgcn_mfma_f32_16x16x32_f16(
                    ag, bfr[nt], accG[mt][nt], 0, 0, 0);
            }
        }
    }

    float s = 0.f;
#pragma unroll
    for (int mt = 0; mt < 2; ++mt) {
        float4 obA = *(const float4*)(out_b + ga + mt * 16 + quad * 4);
        float4 obG = *(const float4*)(out_b + gg + mt * 16 + quad * 4);
        float4 dv  = *(const float4*)(dec_w + ga + mt * 16 + quad * 4);
#pragma unroll
        for (int nt = 0; nt < 4; ++nt) {
#pragma unroll
            for (int r = 0; r < 4; ++r) {
                float a  = accA[mt][nt][r] + ((const float*)&obA)[r];
                float zg = accG[mt][nt][r] + ((const float*)&obG)[r];
                float sig = __fdividef(1.f, 1.f + __expf(-zg));
                s = fmaf(((const float*)&dv)[r], a * sig, s);
            }
        }
    }
#pragma unroll
    for (int off = 32; off; off >>= 1) s += __shfl_down(s, off, 64);
    if (lane == 0) red[wq] = s;
    __syncthreads();
    if (tid == 0) part[blk] = red[0] + red[1] + red[2] + red[3];
}

// ---------------------------------------------------------------------------
__global__ __launch_bounds__(512) void k_final(
    const float* __restrict__ part, const float* __restrict__ dec_b,
    float* __restrict__ out)
{
    int tid = threadIdx.x;
    int b = tid >> 6, lane = tid & 63;
    float s = part[b * 128 + lane] + part[b * 128 + 64 + lane];
#pragma unroll
    for (int off = 32; off; off >>= 1) s += __shfl_down(s, off, 64);
    if (lane == 0) out[b] = fmaf(s, 1.0f / (float)L_, dec_b[0]);
}

// ---------------------------------------------------------------------------
extern "C" void kernel_launch(void* const* d_in, const int* in_sizes, int n_in,
                              void* d_out, int out_size, void* d_ws, size_t ws_size,
                              hipStream_t stream)
{
    const float* x         = (const float*)d_in[0];
    const float* enc_w     = (const float*)d_in[1];
    const float* enc_b     = (const float*)d_in[2];
    const float* log_dt    = (const float*)d_in[3];
    const float* log_A_real= (const float*)d_in[4];
    const float* A_imag    = (const float*)d_in[5];
    const float* C_re      = (const float*)d_in[6];
    const float* C_im      = (const float*)d_in[7];
    const float* Dp        = (const float*)d_in[8];
    const float* out_w     = (const float*)d_in[9];
    const float* out_b     = (const float*)d_in[10];
    const float* dec_w     = (const float*)d_in[11];
    const float* dec_b     = (const float*)d_in[12];
    float* out = (float*)d_out;

    char* ws = (char*)d_ws;
    unsigned short* Wh = (unsigned short*)(ws);
    unsigned short* Kh = (unsigned short*)(ws + 65536);
    unsigned short* Ph = (unsigned short*)(ws + 1114112);
    unsigned short* Vh = (unsigned short*)(ws + 2162688);
    float* gy   = (float*)(ws + 3211264);
    float* part = (float*)(ws + 36765696);

    k_prep<<<H_, 256, 0, stream>>>(log_dt, log_A_real, A_imag, C_re, C_im,
                                   out_w, Wh, Kh, Ph, Vh);
    k_s4d<<<B_ * H_, 256, 0, stream>>>(x, enc_w, enc_b, log_dt, log_A_real,
                                       A_imag, Dp, Kh, Ph, Vh, gy);
    k_mix<<<B_ * 128, 256, 0, stream>>>(Wh, gy, out_b, dec_w, part);
    k_final<<<1, 512, 0, stream>>>(part, dec_b, out);
}

// Round 14
// 138.995 us; speedup vs baseline: 1.4024x; 1.0388x over previous
//
#include <hip/hip_runtime.h>
#include <math.h>

// Problem dims (fixed by the reference)
#define B_ 8
#define L_ 8192
#define H_ 128
#define N_ 32
#define C_ 128   // chunks along L
#define T_ 64    // chunk length

// ws layout:
//   Wh   ushort[256*128]     @ 0        (64 KB)  fp16 out_w [g][h]
//   Kh   ushort[128*64*64]   @ 65536    (1 MB)   fp16 Klo[h][t][j] (Toeplitz)
//   Ph   ushort[128*64*64]   @ 1114112  (1 MB)   fp16 P[h][t][m']  (state inj)
//   Vh   ushort[128*64*64]   @ 2162688  (1 MB)   fp16 V[h][m'][j]  (Vandermonde)
//   gy   ushort[B_*H_*L_]    @ 3211264  (16 MB)  fp16 gy [b][h][l'], l'=t*128+c
//   part float[1024]         @ 19988480 (4 KB)
// gy fp16 is numerically free: k_mix already converted gy->fp16 before MFMA.

typedef _Float16 half8 __attribute__((ext_vector_type(8)));
typedef __attribute__((ext_vector_type(4))) float f32x4;

__device__ __forceinline__ float gelu_tanh(float y) {
    float t = 0.7978845608028654f * fmaf(0.044715f, y * y * y, y);
    float e = __expf(2.f * t);
    float th = 1.f - __fdividef(2.f, e + 1.f);
    return 0.5f * y * (1.f + th);
}
__device__ __forceinline__ unsigned short f2h(float f) {
    _Float16 h = (_Float16)f;
    return *(unsigned short*)&h;
}
__device__ __forceinline__ float h2f(unsigned short u) {
    return (float)(*(const _Float16*)&u);
}

// ---------------------------------------------------------------------------
// k_prep: per-h fp16 matrices Klo/P/V + Wh (out_w fp16). Block = h. (unchanged)
// ---------------------------------------------------------------------------
__global__ __launch_bounds__(256) void k_prep(
    const float* __restrict__ log_dt, const float* __restrict__ log_A_real,
    const float* __restrict__ A_imag, const float* __restrict__ C_re,
    const float* __restrict__ C_im, const float* __restrict__ out_w,
    unsigned short* __restrict__ Wh, unsigned short* __restrict__ Kh,
    unsigned short* __restrict__ Ph, unsigned short* __restrict__ Vh)
{
    const int h = blockIdx.x;
    const int tid = threadIdx.x;
    __shared__ float2 wtab[65][N_];
    __shared__ float2 coefs[N_];
    __shared__ float Kd[64];

    float dt = expf(log_dt[h]);
#pragma unroll
    for (int it = 0; it < 9; ++it) {
        int idx = it * 256 + tid;
        if (idx < 65 * N_) {
            int d = idx >> 5, n = idx & 31;
            float Ar = -expf(log_A_real[h * N_ + n]);
            float Ai = A_imag[h * N_ + n];
            float ar = dt * Ar * (float)d, ai = dt * Ai * (float)d;
            float er = expf(ar);
            wtab[d][n] = make_float2(er * cosf(ai), er * sinf(ai));
        }
    }
    if (tid < N_) {
        int n = tid;
        float Ar = -expf(log_A_real[h * N_ + n]);
        float Ai = A_imag[h * N_ + n];
        float ar = dt * Ar, ai = dt * Ai;
        float er = expf(ar);
        float wr = er * cosf(ai), wi = er * sinf(ai);
        float inv = 1.f / (Ar * Ar + Ai * Ai);
        float numr = wr - 1.f, numi = wi;
        float qr = (numr * Ar + numi * Ai) * inv;
        float qi = (numi * Ar - numr * Ai) * inv;
        coefs[n] = make_float2(C_re[h * N_ + n] * qr - C_im[h * N_ + n] * qi,
                               C_re[h * N_ + n] * qi + C_im[h * N_ + n] * qr);
    }
    __syncthreads();
    if (tid < 64) {
        float s = 0.f;
#pragma unroll
        for (int n = 0; n < N_; ++n) {
            float2 cf = coefs[n]; float2 w = wtab[tid][n];
            s += cf.x * w.x - cf.y * w.y;
        }
        Kd[tid] = 2.f * s;
    }
    __syncthreads();
#pragma unroll
    for (int it = 0; it < 16; ++it) {
        int idx = it * 256 + tid;              // t*64 + j
        int t = idx >> 6, j = idx & 63;
        Kh[h * 4096 + idx] = f2h((t >= j) ? Kd[t - j] : 0.f);
    }
#pragma unroll
    for (int it = 0; it < 16; ++it) {
        int idx = it * 256 + tid;              // t*64 + m
        int t = idx >> 6, m = idx & 63, n = m & 31;
        float2 cf = coefs[n]; float2 w = wtab[t + 1][n];
        float re = cf.x * w.x - cf.y * w.y;
        float im = cf.x * w.y + cf.y * w.x;
        Ph[h * 4096 + idx] = f2h((m < 32) ? 2.f * re : -2.f * im);
    }
#pragma unroll
    for (int it = 0; it < 16; ++it) {
        int idx = it * 256 + tid;              // m*64 + j
        int m = idx >> 6, j = idx & 63, n = m & 31;
        float2 w = wtab[63 - j][n];
        Vh[h * 4096 + idx] = f2h((m < 32) ? w.x : w.y);
    }
    {   // out_w rows g = 2h, 2h+1 -> fp16
        int g = 2 * h + (tid >> 7), j = tid & 127;
        Wh[g * 128 + j] = f2h(out_w[g * 128 + j]);
    }
}

// ---------------------------------------------------------------------------
// k_s4d: MFMA-Toeplitz S4D (R13 structure). Only change: gy stored fp16
// (block-private contiguous 16 KB; quads write full 32B sectors — NOT the
// R7 cross-block strided 2B pattern).
// ---------------------------------------------------------------------------
__global__ __launch_bounds__(256) void k_s4d(
    const float* __restrict__ x, const float* __restrict__ enc_w,
    const float* __restrict__ enc_b, const float* __restrict__ log_dt,
    const float* __restrict__ log_A_real, const float* __restrict__ A_imag,
    const float* __restrict__ Dp, const unsigned short* __restrict__ Kh,
    const unsigned short* __restrict__ Ph, const unsigned short* __restrict__ Vh,
    unsigned short* __restrict__ gy)
{
    const int bh = blockIdx.x;
    const int b = bh >> 7, h = bh & (H_ - 1);
    const int tid = threadIdx.x;
    const int lane = tid & 63, wq = tid >> 6;
    const int mrow = lane & 15, quad = lane >> 4;

    __shared__ unsigned short Ut[C_][72];          // [c][j] fp16 u (18.4 KB)
    __shared__ __align__(16) char scratch[18432];  // E16 / Sx / St (18.4 KB)
    __shared__ float2 wTpow[7][N_];                // 1.8 KB
    unsigned short* E16 = (unsigned short*)scratch;   // [m(64)][c] stride 136
    float2*         Sx  = (float2*)scratch;           // [n(32)][c(64)]
    unsigned short* St  = (unsigned short*)scratch;   // [c(128)][m'] stride 72

    if (tid < N_) {
        int idx = h * N_ + tid;
        float dt = expf(log_dt[h]);
        float Ar = -expf(log_A_real[idx]);
        float Ai = A_imag[idx];
        float ar = dt * Ar * (float)T_, ai = dt * Ai * (float)T_;
        float er = expf(ar);
        float pr = er * cosf(ai), pi = er * sinf(ai);
#pragma unroll
        for (int k = 0; k < 7; ++k) {
            wTpow[k][tid] = make_float2(pr, pi);
            float nr = pr * pr - pi * pi;
            pi = 2.f * pr * pi; pr = nr;
        }
    }

    // ---- stage: u = enc(x) -> Ut[c][j] fp16 ----
    const float ew0 = enc_w[h], ew1 = enc_w[H_ + h], eb = enc_b[h];
    {
        int c = tid >> 1, j0 = (tid & 1) * 32;
        const float4* xp = (const float4*)((const float2*)x + (size_t)b * L_
                                           + c * 64 + j0);
#pragma unroll
        for (int i = 0; i < 16; ++i) {
            float4 xv = xp[i];
            float u0 = fmaf(xv.x, ew0, fmaf(xv.y, ew1, eb));
            float u1 = fmaf(xv.z, ew0, fmaf(xv.w, ew1, eb));
            unsigned int pk = (unsigned)f2h(u0) | ((unsigned)f2h(u1) << 16);
            *(unsigned int*)&Ut[c][j0 + 2 * i] = pk;
        }
    }
    __syncthreads();

    // ---- GEMM E[m 64][c 128] = V[m][j] @ U[j][c] -> fp16 E16 ----
    {
        f32x4 acc[8];
#pragma unroll
        for (int nt = 0; nt < 8; ++nt) acc[nt] = (f32x4){0.f, 0.f, 0.f, 0.f};
        const unsigned short* Arow = Vh + h * 4096 + (wq * 16 + mrow) * 64;
#pragma unroll
        for (int ks = 0; ks < 2; ++ks) {
            int k0 = ks * 32 + quad * 8;
            half8 af = *(const half8*)(Arow + k0);
#pragma unroll
            for (int nt = 0; nt < 8; ++nt) {
                half8 bf = *(const half8*)&Ut[nt * 16 + mrow][k0];
                acc[nt] = __builtin_amdgcn_mfma_f32_16x16x32_f16(
                    af, bf, acc[nt], 0, 0, 0);
            }
        }
#pragma unroll
        for (int nt = 0; nt < 8; ++nt) {
            int cc = nt * 16 + mrow;
#pragma unroll
            for (int r = 0; r < 4; ++r)
                E16[(wq * 16 + quad * 4 + r) * 136 + cc] = f2h(acc[nt][r]);
        }
    }
    __syncthreads();

    // ---- scan: 4 waves, wave = (cHalf, nHalf), 16 n per thread ----
    float zr[16], zi[16];
    const int cHalf = wq & 1, nHalf = wq >> 1;
    const int n0 = nHalf * 16;
    const int c = cHalf * 64 + lane;
#pragma unroll
    for (int j = 0; j < 16; ++j) {
        zr[j] = h2f(E16[(n0 + j) * 136 + c]);
        zi[j] = h2f(E16[(32 + n0 + j) * 136 + c]);
    }
    __syncthreads();            // all E16 reads done before Sx overwrites
#pragma unroll
    for (int k = 0; k < 6; ++k) {
        int s = 1 << k;
        float mask = (lane >= s) ? 1.f : 0.f;
#pragma unroll
        for (int j = 0; j < 16; ++j) {
            float2 q = wTpow[k][n0 + j];
            float vr = __shfl_up(zr[j], s, 64);
            float vi = __shfl_up(zi[j], s, 64);
            float adr = fmaf(q.x, vr, -(q.y * vi));
            float adi = fmaf(q.x, vi, q.y * vr);
            zr[j] = fmaf(mask, adr, zr[j]);
            zi[j] = fmaf(mask, adi, zi[j]);
        }
    }
    if (cHalf == 0) {           // publish inclusive scans of low c-half
#pragma unroll
        for (int j = 0; j < 16; ++j)
            Sx[(n0 + j) * 64 + lane] = make_float2(zr[j], zi[j]);
    }
    __syncthreads();
    if (cHalf == 1) {           // s=64 combine with uniform weight wT^64
#pragma unroll
        for (int j = 0; j < 16; ++j) {
            float2 q = wTpow[6][n0 + j];
            float2 v = Sx[(n0 + j) * 64 + lane];
            zr[j] = fmaf(q.x, v.x, fmaf(-q.y, v.y, zr[j]));
            zi[j] = fmaf(q.x, v.y, fmaf(q.y, v.x, zi[j]));
        }
    }
    {                           // shift by one chunk: S_in[c] = I[c-1]
        bool l0 = (lane == 0);
#pragma unroll
        for (int j = 0; j < 16; ++j) {
            float2 bv = Sx[(n0 + j) * 64 + 63];
            float br = (cHalf == 1) ? bv.x : 0.f;
            float bi = (cHalf == 1) ? bv.y : 0.f;
            float tr = __shfl_up(zr[j], 1, 64);
            float ti = __shfl_up(zi[j], 1, 64);
            zr[j] = l0 ? br : tr;
            zi[j] = l0 ? bi : ti;
        }
    }
    __syncthreads();            // all Sx reads done before St overwrites
    {
#pragma unroll
        for (int j2 = 0; j2 < 8; ++j2) {
            unsigned int p0 = (unsigned)f2h(zr[2 * j2]) |
                              ((unsigned)f2h(zr[2 * j2 + 1]) << 16);
            unsigned int p1 = (unsigned)f2h(zi[2 * j2]) |
                              ((unsigned)f2h(zi[2 * j2 + 1]) << 16);
            *(unsigned int*)&St[c * 72 + n0 + 2 * j2] = p0;
            *(unsigned int*)&St[c * 72 + 32 + n0 + 2 * j2] = p1;
        }
    }
    __syncthreads();

    // ---- GEMM Y[t][c] = Klo@U + P@S; epilogue u from Ut; fp16 gy store ----
    {
        f32x4 acc[8];
#pragma unroll
        for (int nt = 0; nt < 8; ++nt) acc[nt] = (f32x4){0.f, 0.f, 0.f, 0.f};
        const unsigned short* Krow = Kh + h * 4096 + (wq * 16 + mrow) * 64;
#pragma unroll
        for (int ks = 0; ks < 2; ++ks) {
            int k0 = ks * 32 + quad * 8;
            half8 af = *(const half8*)(Krow + k0);
#pragma unroll
            for (int nt = 0; nt < 8; ++nt) {
                half8 bf = *(const half8*)&Ut[nt * 16 + mrow][k0];
                acc[nt] = __builtin_amdgcn_mfma_f32_16x16x32_f16(
                    af, bf, acc[nt], 0, 0, 0);
            }
        }
        const unsigned short* Prow = Ph + h * 4096 + (wq * 16 + mrow) * 64;
#pragma unroll
        for (int ks = 0; ks < 2; ++ks) {
            int k0 = ks * 32 + quad * 8;
            half8 af = *(const half8*)(Prow + k0);
#pragma unroll
            for (int nt = 0; nt < 8; ++nt) {
                half8 bf = *(const half8*)&St[(nt * 16 + mrow) * 72 + k0];
                acc[nt] = __builtin_amdgcn_mfma_f32_16x16x32_f16(
                    af, bf, acc[nt], 0, 0, 0);
            }
        }
        const float Dh = Dp[h];
        unsigned short* gyb = gy + (size_t)bh * L_;
#pragma unroll
        for (int nt = 0; nt < 8; ++nt) {
            int cc = nt * 16 + mrow;
#pragma unroll
            for (int r = 0; r < 4; ++r) {
                int t = wq * 16 + quad * 4 + r;
                float u = h2f(Ut[cc][t]);
                float y = fmaf(Dh, u, acc[nt][r]);
                gyb[t * 128 + cc] = f2h(gelu_tanh(y));
            }
        }
    }
}

// ---------------------------------------------------------------------------
// k_mix: fp16 MFMA GLU mix + pooled decode. Staging now a pure ushort
// transpose (uint4 loads of 8 fp16); MFMA/epilogue unchanged from R12/R13.
// ---------------------------------------------------------------------------
#define BPAD 136
__global__ __launch_bounds__(256) void k_mix(
    const unsigned short* __restrict__ Wh, const unsigned short* __restrict__ gy,
    const float* __restrict__ out_b, const float* __restrict__ dec_w,
    float* __restrict__ part)
{
    __shared__ unsigned short Bt[64 * BPAD];   // [v][h] fp16 tile (17.4 KB)
    __shared__ float red[4];

    const int blk = blockIdx.x;                // = b*128 + t*2 + ch
    const int b = blk >> 7;
    const int t = (blk >> 1) & 63, ch = blk & 1;
    const int tid = threadIdx.x;
    const int wq = tid >> 6, lane = tid & 63;

    // ---- stage: 128h x 64v fp16 transpose (uint4 = 8 ushorts per load) ----
    const unsigned short* gsrc = gy + (size_t)(b * H_) * L_ + t * 128 + ch * 64;
#pragma unroll
    for (int it = 0; it < 4; ++it) {
        int idx = it * 256 + tid;              // 0..1023; h = idx/8, v0=(idx&7)*8
        int h = idx >> 3, v0 = (idx & 7) * 8;
        uint4 q = *(const uint4*)(gsrc + (size_t)h * L_ + v0);
        Bt[(v0 + 0) * BPAD + h] = (unsigned short)(q.x & 0xFFFF);
        Bt[(v0 + 1) * BPAD + h] = (unsigned short)(q.x >> 16);
        Bt[(v0 + 2) * BPAD + h] = (unsigned short)(q.y & 0xFFFF);
        Bt[(v0 + 3) * BPAD + h] = (unsigned short)(q.y >> 16);
        Bt[(v0 + 4) * BPAD + h] = (unsigned short)(q.z & 0xFFFF);
        Bt[(v0 + 5) * BPAD + h] = (unsigned short)(q.z >> 16);
        Bt[(v0 + 6) * BPAD + h] = (unsigned short)(q.w & 0xFFFF);
        Bt[(v0 + 7) * BPAD + h] = (unsigned short)(q.w >> 16);
    }
    __syncthreads();

    const int ga = wq * 32;
    const int gg = 128 + wq * 32;
    const int mrow = lane & 15;
    const int quad = lane >> 4;
    f32x4 accA[2][4], accG[2][4];
#pragma unroll
    for (int mt = 0; mt < 2; ++mt)
#pragma unroll
        for (int nt = 0; nt < 4; ++nt) {
            accA[mt][nt] = (f32x4){0.f, 0.f, 0.f, 0.f};
            accG[mt][nt] = (f32x4){0.f, 0.f, 0.f, 0.f};
        }

#pragma unroll
    for (int k = 0; k < 4; ++k) {
        const int h0 = k * 32 + quad * 8;
        half8 bfr[4];
#pragma unroll
        for (int nt = 0; nt < 4; ++nt) {
            int v = nt * 16 + mrow;
            bfr[nt] = *(const half8*)(Bt + v * BPAD + h0);
        }
#pragma unroll
        for (int mt = 0; mt < 2; ++mt) {
            half8 ah = *(const half8*)(Wh + (ga + mt * 16 + mrow) * 128 + h0);
            half8 ag = *(const half8*)(Wh + (gg + mt * 16 + mrow) * 128 + h0);
#pragma unroll
            for (int nt = 0; nt < 4; ++nt) {
                accA[mt][nt] = __builtin_amdgcn_mfma_f32_16x16x32_f16(
                    ah, bfr[nt], accA[mt][nt], 0, 0, 0);
                accG[mt][nt] = __builtin_amdgcn_mfma_f32_16x16x32_f16(
                    ag, bfr[nt], accG[mt][nt], 0, 0, 0);
            }
        }
    }

    float s = 0.f;
#pragma unroll
    for (int mt = 0; mt < 2; ++mt) {
        float4 obA = *(const float4*)(out_b + ga + mt * 16 + quad * 4);
        float4 obG = *(const float4*)(out_b + gg + mt * 16 + quad * 4);
        float4 dv  = *(const float4*)(dec_w + ga + mt * 16 + quad * 4);
#pragma unroll
        for (int nt = 0; nt < 4; ++nt) {
#pragma unroll
            for (int r = 0; r < 4; ++r) {
                float a  = accA[mt][nt][r] + ((const float*)&obA)[r];
                float zg = accG[mt][nt][r] + ((const float*)&obG)[r];
                float sig = __fdividef(1.f, 1.f + __expf(-zg));
                s = fmaf(((const float*)&dv)[r], a * sig, s);
            }
        }
    }
#pragma unroll
    for (int off = 32; off; off >>= 1) s += __shfl_down(s, off, 64);
    if (lane == 0) red[wq] = s;
    __syncthreads();
    if (tid == 0) part[blk] = red[0] + red[1] + red[2] + red[3];
}

// ---------------------------------------------------------------------------
__global__ __launch_bounds__(512) void k_final(
    const float* __restrict__ part, const float* __restrict__ dec_b,
    float* __restrict__ out)
{
    int tid = threadIdx.x;
    int b = tid >> 6, lane = tid & 63;
    float s = part[b * 128 + lane] + part[b * 128 + 64 + lane];
#pragma unroll
    for (int off = 32; off; off >>= 1) s += __shfl_down(s, off, 64);
    if (lane == 0) out[b] = fmaf(s, 1.0f / (float)L_, dec_b[0]);
}

// ---------------------------------------------------------------------------
extern "C" void kernel_launch(void* const* d_in, const int* in_sizes, int n_in,
                              void* d_out, int out_size, void* d_ws, size_t ws_size,
                              hipStream_t stream)
{
    const float* x         = (const float*)d_in[0];
    const float* enc_w     = (const float*)d_in[1];
    const float* enc_b     = (const float*)d_in[2];
    const float* log_dt    = (const float*)d_in[3];
    const float* log_A_real= (const float*)d_in[4];
    const float* A_imag    = (const float*)d_in[5];
    const float* C_re      = (const float*)d_in[6];
    const float* C_im      = (const float*)d_in[7];
    const float* Dp        = (const float*)d_in[8];
    const float* out_w     = (const float*)d_in[9];
    const float* out_b     = (const float*)d_in[10];
    const float* dec_w     = (const float*)d_in[11];
    const float* dec_b     = (const float*)d_in[12];
    float* out = (float*)d_out;

    char* ws = (char*)d_ws;
    unsigned short* Wh = (unsigned short*)(ws);
    unsigned short* Kh = (unsigned short*)(ws + 65536);
    unsigned short* Ph = (unsigned short*)(ws + 1114112);
    unsigned short* Vh = (unsigned short*)(ws + 2162688);
    unsigned short* gy = (unsigned short*)(ws + 3211264);
    float* part = (float*)(ws + 19988480);

    k_prep<<<H_, 256, 0, stream>>>(log_dt, log_A_real, A_imag, C_re, C_im,
                                   out_w, Wh, Kh, Ph, Vh);
    k_s4d<<<B_ * H_, 256, 0, stream>>>(x, enc_w, enc_b, log_dt, log_A_real,
                                       A_imag, Dp, Kh, Ph, Vh, gy);
    k_mix<<<B_ * 128, 256, 0, stream>>>(Wh, gy, out_b, dec_w, part);
    k_final<<<1, 512, 0, stream>>>(part, dec_b, out);
}